// Round 2
// baseline (513.224 us; speedup 1.0000x reference)
//
#include <hip/hip_runtime.h>
#include <hip/hip_bf16.h>
#include <math.h>

typedef __bf16 bf16_t;
typedef __bf16 bf16x8 __attribute__((ext_vector_type(8)));
typedef float f32x4 __attribute__((ext_vector_type(4)));

#define AS1q __attribute__((address_space(1)))
#define AS3q __attribute__((address_space(3)))

// async global->LDS, 16B per lane; LDS dest = wave-uniform base + lane*16
__device__ __forceinline__ void gload_lds16(const bf16_t* g, bf16_t* l) {
    __builtin_amdgcn_global_load_lds((AS1q void*)g, (AS3q void*)l, 16, 0, 0);
}

// ------------------------------------------------------------------
// constants for this problem (B=1, H=W=T=48, C=96, nh=3, hd=32)
// ------------------------------------------------------------------
#define LROWS   110592        // H*W*T
#define CDIM    96
#define NTOK    2304          // H*W
#define FDIM    1536          // B_*hd
#define YSTR    3538944ll     // 2304*1536 (per-g stride in Y)
#define SSTR    5308416ll     // 2304*2304
#define SCALE_Q 0.1767766952966369f   // 32^-0.5

// ------------------------------------------------------------------
// weight fp32 -> bf16 (qkv 27648 | proj 9216 | fc1 36864 | fc2 36864)
// ------------------------------------------------------------------
__global__ __launch_bounds__(256)
void conv_w(const float* __restrict__ a, const float* __restrict__ b,
            const float* __restrict__ c, const float* __restrict__ d,
            bf16_t* __restrict__ out)
{
    int i = blockIdx.x * 256 + threadIdx.x;   // 110592 total
    float v;
    if (i < 27648)       v = a[i];
    else if (i < 36864)  v = b[i - 27648];
    else if (i < 73728)  v = c[i - 36864];
    else                 v = d[i - 73728];
    out[i] = (bf16_t)v;
}

// ------------------------------------------------------------------
// LayerNorm over C=96, one wave per row; optional axial permute on output:
// src row l = n*48 + t  ->  dst row t*2304 + n
// ------------------------------------------------------------------
__global__ __launch_bounds__(256)
void ln_kernel(const float* __restrict__ x, const float* __restrict__ gamma,
               const float* __restrict__ beta, bf16_t* __restrict__ out, int permute)
{
    int wave = threadIdx.x >> 6, lane = threadIdx.x & 63;
    int row = blockIdx.x * 4 + wave;
    const float* xr = x + (size_t)row * CDIM;
    float e0 = xr[lane];
    float e1 = (lane < 32) ? xr[64 + lane] : 0.f;
    float s = e0 + e1;
    for (int off = 32; off > 0; off >>= 1) s += __shfl_xor(s, off, 64);
    float mean = s * (1.f / 96.f);
    float d0 = e0 - mean;
    float d1 = (lane < 32) ? (e1 - mean) : 0.f;
    float vs = d0 * d0 + d1 * d1;
    for (int off = 32; off > 0; off >>= 1) vs += __shfl_xor(vs, off, 64);
    float rstd = rsqrtf(vs * (1.f / 96.f) + 1e-5f);
    size_t orow = row;
    if (permute) { int t = row % 48; int n = row / 48; orow = (size_t)t * NTOK + n; }
    bf16_t* o = out + orow * CDIM;
    o[lane] = (bf16_t)(d0 * rstd * gamma[lane] + beta[lane]);
    if (lane < 32) o[64 + lane] = (bf16_t)(d1 * rstd * gamma[64 + lane] + beta[64 + lane]);
}

// ------------------------------------------------------------------
// V transpose: Y[6+z][n][m] -> Yv[z][m][n]   (64x64 LDS tiles)
// ------------------------------------------------------------------
__global__ __launch_bounds__(256)
void transpose_v(const bf16_t* __restrict__ Y, bf16_t* __restrict__ Yv)
{
    __shared__ bf16_t tile[64][65];
    const bf16_t* src = Y + (size_t)(6 + blockIdx.z) * YSTR;
    bf16_t* dst = Yv + (size_t)blockIdx.z * YSTR;
    int m0 = blockIdx.x * 64, n0 = blockIdx.y * 64;
    int nl = threadIdx.x >> 2, ch = threadIdx.x & 3;
    const bf16x8* s8 = (const bf16x8*)(src + (size_t)(n0 + nl) * FDIM + m0 + ch * 16);
    bf16x8 va = s8[0], vb = s8[1];
    #pragma unroll
    for (int j = 0; j < 8; j++) tile[nl][ch * 16 + j] = va[j];
    #pragma unroll
    for (int j = 0; j < 8; j++) tile[nl][ch * 16 + 8 + j] = vb[j];
    __syncthreads();
    bf16_t* d = dst + (size_t)(m0 + nl) * NTOK + n0 + ch * 16;
    #pragma unroll
    for (int j = 0; j < 16; j++) d[j] = tile[ch * 16 + j][nl];
}

// ------------------------------------------------------------------
// row softmax over 2304: S (f32) -> P (bf16).  One block (256 thr) per row.
// ------------------------------------------------------------------
__global__ __launch_bounds__(256)
void softmax_k(const float* __restrict__ S, bf16_t* __restrict__ P,
               long long sZ, long long pZ)
{
    __shared__ float red[8];
    const float* sr = S + (size_t)blockIdx.z * sZ + (size_t)blockIdx.x * NTOK;
    bf16_t* pr = P + (size_t)blockIdx.z * pZ + (size_t)blockIdx.x * NTOK;
    int wave = threadIdx.x >> 6, lane = threadIdx.x & 63;
    float v[9];
    float mx = -1e30f;
    #pragma unroll
    for (int t = 0; t < 9; t++) { v[t] = sr[t * 256 + threadIdx.x]; mx = fmaxf(mx, v[t]); }
    for (int off = 32; off > 0; off >>= 1) mx = fmaxf(mx, __shfl_xor(mx, off, 64));
    if (lane == 0) red[wave] = mx;
    __syncthreads();
    mx = fmaxf(fmaxf(red[0], red[1]), fmaxf(red[2], red[3]));
    float sum = 0.f;
    #pragma unroll
    for (int t = 0; t < 9; t++) { v[t] = __expf(v[t] - mx); sum += v[t]; }
    for (int off = 32; off > 0; off >>= 1) sum += __shfl_xor(sum, off, 64);
    if (lane == 0) red[4 + wave] = sum;
    __syncthreads();
    sum = red[4] + red[5] + red[6] + red[7];
    float inv = 1.f / sum;
    #pragma unroll
    for (int t = 0; t < 9; t++) pr[t * 256 + threadIdx.x] = (bf16_t)(v[t] * inv);
}

// ------------------------------------------------------------------
// bf16 MFMA GEMM:  C[M,N] = A[M,K] @ W[N,K]^T  (+ fused epilogue)
// BK=32, 256 threads.  BM=128: 2x2 waves of 64x(BN/2).
//                      BM=64 : 1x4 waves of 64x(BN/4).
// XOR swizzle (r>>1)&3 spreads each quad's 16 lanes across all 32 banks
// (2-way aliasing = free; the old (r&3) pattern hit 16 banks -> 4-way).
// EPI: 0=QKV scatter(+bias)  1=S f32 (*scale)  2=PV scatter (o_rows)
//      3=bias+GELU bf16      4=bias+residual f32
// ------------------------------------------------------------------
template<int BM, int BN, int EPI>
__global__ __launch_bounds__(256, 2)
void gemm_bt(const bf16_t* __restrict__ A, const bf16_t* __restrict__ W,
             void* __restrict__ out, const float* __restrict__ bias,
             const float* __restrict__ resid, int K, int ldo,
             long long aZ, long long wZ, long long oZ, float scale, int head0)
{
    constexpr int BK = 32;
    constexpr int WM = (BM == 128) ? 2 : 1;   // wave grid m
    constexpr int WN = 4 / WM;                // wave grid n
    constexpr int MI = BM / (WM * 16);        // m-tiles per wave (=4)
    constexpr int NT = BN / (WN * 16);        // n-tiles per wave
    __shared__ bf16_t As[BM * BK];
    __shared__ bf16_t Bs[BN * BK];

    const int tid = threadIdx.x;
    const int wave = tid >> 6, lane = tid & 63;
    const int quad = lane >> 4, l16 = lane & 15;
    const int wm = (WM == 2) ? (wave & 1) : 0;
    const int wn = (WM == 2) ? (wave >> 1) : wave;
    const int z = blockIdx.z;
    A += (size_t)z * aZ;
    W += (size_t)z * wZ;
    const int m0 = blockIdx.x * BM, n0 = blockIdx.y * BN;

    f32x4 acc[MI][NT];
    #pragma unroll
    for (int i = 0; i < MI; i++)
        #pragma unroll
        for (int j = 0; j < NT; j++) { f32x4 zz = {0.f, 0.f, 0.f, 0.f}; acc[i][j] = zz; }

    const int srow = lane >> 2;   // row within a 16-row issue
    const int scol = lane & 3;    // 16B chunk slot

    for (int k0 = 0; k0 < K; k0 += BK) {
        __syncthreads();   // prior compute done reading LDS
        for (int it = wave; it < BM / 16; it += 4) {
            int r = it * 16 + srow;
            int cg = scol ^ ((r >> 1) & 3);              // XOR swizzle
            gload_lds16(A + (size_t)(m0 + r) * K + k0 + cg * 8, &As[it * 512]);
        }
        for (int it = wave; it < BN / 16; it += 4) {
            int r = it * 16 + srow;
            int cg = scol ^ ((r >> 1) & 3);
            gload_lds16(W + (size_t)(n0 + r) * K + k0 + cg * 8, &Bs[it * 512]);
        }
        __syncthreads();   // barrier emits vmcnt(0) drain -> LDS valid

        bf16x8 af[MI], bfr[NT];
        #pragma unroll
        for (int i = 0; i < MI; i++) {
            int r = wm * 64 + i * 16 + l16;
            af[i] = *(const bf16x8*)&As[r * 32 + ((quad ^ ((r >> 1) & 3)) << 3)];
        }
        #pragma unroll
        for (int j = 0; j < NT; j++) {
            int c = wn * (BN / WN) + j * 16 + l16;
            bfr[j] = *(const bf16x8*)&Bs[c * 32 + ((quad ^ ((c >> 1) & 3)) << 3)];
        }
        #pragma unroll
        for (int i = 0; i < MI; i++)
            #pragma unroll
            for (int j = 0; j < NT; j++)
                acc[i][j] = __builtin_amdgcn_mfma_f32_16x16x32_bf16(af[i], bfr[j], acc[i][j], 0, 0, 0);
    }

    // epilogue: D[row=quad*4+ri][col=l16] per 16x16 tile
    if constexpr (EPI == 0) {
        // QKV scatter: block rows all share t (2304 % 128 == 0)
        const int t = m0 / NTOK;
        const int nb = m0 - t * NTOK;
        #pragma unroll
        for (int j = 0; j < NT; j++) {
            int c = n0 + wn * (BN / WN) + j * 16 + l16;
            int jj = t * 288 + c;
            int g = jj / FDIM;
            int mm = jj - g * FDIM;
            float bv = bias[c];
            bf16_t* yp = (bf16_t*)out + (size_t)g * YSTR + mm;
            #pragma unroll
            for (int i = 0; i < MI; i++)
                #pragma unroll
                for (int ri = 0; ri < 4; ri++) {
                    int n = nb + wm * 64 + i * 16 + quad * 4 + ri;
                    yp[(size_t)n * FDIM] = (bf16_t)(acc[i][j][ri] + bv);
                }
        }
    } else {
        #pragma unroll
        for (int i = 0; i < MI; i++)
            #pragma unroll
            for (int j = 0; j < NT; j++)
                #pragma unroll
                for (int ri = 0; ri < 4; ri++) {
                    int r = m0 + wm * 64 + i * 16 + quad * 4 + ri;
                    int c = n0 + wn * (BN / WN) + j * 16 + l16;
                    float v = acc[i][j][ri];
                    if constexpr (EPI == 1) {
                        float* op = (float*)out + (size_t)z * oZ;
                        op[(size_t)r * NTOK + c] = v * scale;
                    } else if constexpr (EPI == 2) {
                        int h = head0 + z;
                        int b = r / 48, rr = r - b * 48;
                        ((bf16_t*)out)[((size_t)(b * NTOK + rr * 48 + h * 16)) * CDIM + c] = (bf16_t)v;
                    } else if constexpr (EPI == 3) {
                        float u = v + bias[c];
                        u = 0.5f * u * (1.0f + erff(u * 0.70710678118654752f));
                        ((bf16_t*)out)[(size_t)r * ldo + c] = (bf16_t)u;
                    } else {
                        float u = v + bias[c] + resid[(size_t)r * ldo + c];
                        ((float*)out)[(size_t)r * ldo + c] = u;
                    }
                }
    }
}

// ------------------------------------------------------------------
extern "C" void kernel_launch(void* const* d_in, const int* in_sizes, int n_in,
                              void* d_out, int out_size, void* d_ws, size_t ws_size,
                              hipStream_t stream)
{
    const float* x      = (const float*)d_in[0];
    const float* ln1_g  = (const float*)d_in[2];
    const float* ln1_b  = (const float*)d_in[3];
    const float* qkv_w  = (const float*)d_in[4];
    const float* qkv_b  = (const float*)d_in[5];
    const float* proj_w = (const float*)d_in[6];
    const float* proj_b = (const float*)d_in[7];
    const float* ln2_g  = (const float*)d_in[8];
    const float* ln2_b  = (const float*)d_in[9];
    const float* fc1_w  = (const float*)d_in[10];
    const float* fc1_b  = (const float*)d_in[11];
    const float* fc2_w  = (const float*)d_in[12];
    const float* fc2_b  = (const float*)d_in[13];

    // ---- workspace layout (all sizes 256B-multiples) ----
    const size_t SZ_WB = 110592ull * 2;          // bf16 weights
    const size_t SZ_HP = 10616832ull * 2;        // hp / o_rows / h2
    const size_t SZ_Y  = 31850496ull * 2;        // Y [9][2304][1536]
    const size_t SZ_YV = 10616832ull * 2;        // Yv [3][1536][2304]
    const size_t SZ_S1 = 5308416ull * 4;         // S per head (f32)
    const size_t SZ_P1 = 5308416ull * 2;         // P per head (bf16)
    const size_t SZ_X2 = 10616832ull * 4;        // x2 (f32)

    char* ws = (char*)d_ws;
    size_t oWB = 0;
    size_t oHP = oWB + SZ_WB;
    size_t oY  = oHP + SZ_HP;
    size_t oYV = oY + SZ_Y;
    size_t oS  = oYV + SZ_YV;
    size_t needBig   = oS + 3 * SZ_S1 + 3 * SZ_P1 + SZ_X2;
    bool big = (ws_size >= needBig);
    size_t oP  = oS + (big ? 3 * SZ_S1 : SZ_S1);
    size_t oX2 = oP + (big ? 3 * SZ_P1 : SZ_P1);

    bf16_t* Wb    = (bf16_t*)(ws + oWB);
    bf16_t* Wqkv  = Wb;
    bf16_t* Wproj = Wb + 27648;
    bf16_t* Wfc1  = Wb + 36864;
    bf16_t* Wfc2  = Wb + 73728;
    bf16_t* hp    = (bf16_t*)(ws + oHP);   // then o_rows, then h2
    bf16_t* Y     = (bf16_t*)(ws + oY);
    bf16_t* Yv    = (bf16_t*)(ws + oYV);
    bf16_t* t1    = (bf16_t*)(ws + oY);    // reuses Y+Yv (exact fit)
    float*  Sb    = (float*)(ws + oS);
    bf16_t* Pb    = (bf16_t*)(ws + oP);
    float*  x2    = (float*)(ws + oX2);
    float*  outp  = (float*)d_out;

    dim3 blk(256);

    // 1. weights -> bf16
    conv_w<<<dim3(432), blk, 0, stream>>>(qkv_w, proj_w, fc1_w, fc2_w, Wb);
    // 2. LN1 + axial permute -> hp [48][2304][96]
    ln_kernel<<<dim3(27648), blk, 0, stream>>>(x, ln1_g, ln1_b, hp, 1);
    // 3. QKV gemm -> Y (scattered to [g][n][m])
    gemm_bt<128, 96, 0><<<dim3(864, 3), blk, 0, stream>>>(hp, Wqkv, Y, qkv_b, nullptr,
                                                          96, 0, 0, 0, 0, 0.f, 0);
    // 4. V transpose -> Yv [h][m][n]
    transpose_v<<<dim3(24, 36, 3), blk, 0, stream>>>(Y, Yv);

    // 5-7. attention (BM=64 tiles: S grid 1944 blocks, PV 1296 -> 5-7.6 blk/CU)
    if (big) {
        gemm_bt<64, 128, 1><<<dim3(36, 18, 3), blk, 0, stream>>>(Y, Y + 3 * YSTR, Sb, nullptr, nullptr,
                                                                 1536, 0, YSTR, YSTR, SSTR, SCALE_Q, 0);
        softmax_k<<<dim3(2304, 1, 3), blk, 0, stream>>>(Sb, Pb, SSTR, SSTR);
        gemm_bt<64, 128, 2><<<dim3(36, 12, 3), blk, 0, stream>>>(Pb, Yv, hp, nullptr, nullptr,
                                                                 2304, 0, SSTR, YSTR, 0, 0.f, 0);
    } else {
        for (int h = 0; h < 3; h++) {
            gemm_bt<64, 128, 1><<<dim3(36, 18, 1), blk, 0, stream>>>(Y + (size_t)h * YSTR, Y + (size_t)(3 + h) * YSTR,
                                                                     Sb, nullptr, nullptr,
                                                                     1536, 0, 0, 0, 0, SCALE_Q, 0);
            softmax_k<<<dim3(2304, 1, 1), blk, 0, stream>>>(Sb, Pb, 0, 0);
            gemm_bt<64, 128, 2><<<dim3(36, 12, 1), blk, 0, stream>>>(Pb, Yv + (size_t)h * YSTR, hp, nullptr, nullptr,
                                                                     2304, 0, 0, 0, 0, 0.f, h);
        }
    }

    // 8. proj + residual -> x2 (f32)   (o_rows lives in hp region)
    gemm_bt<128, 96, 4><<<dim3(864, 1), blk, 0, stream>>>(hp, Wproj, x2, proj_b, x,
                                                          96, 96, 0, 0, 0, 0.f, 0);
    // 9. LN2 -> h2 (reuses hp region)
    ln_kernel<<<dim3(27648), blk, 0, stream>>>(x2, ln2_g, ln2_b, hp, 0);
    // 10. fc1 + GELU -> t1 (reuses Y+Yv region)
    gemm_bt<128, 128, 3><<<dim3(864, 3), blk, 0, stream>>>(hp, Wfc1, t1, fc1_b, nullptr,
                                                           96, 384, 0, 0, 0, 0.f, 0);
    // 11. fc2 + residual -> out (f32)
    gemm_bt<128, 96, 4><<<dim3(864, 1), blk, 0, stream>>>(t1, Wfc2, outp, fc2_b, x2,
                                                          384, 96, 0, 0, 0, 0.f, 0);
}

// Round 3
// 487.421 us; speedup vs baseline: 1.0529x; 1.0529x over previous
//
#include <hip/hip_runtime.h>
#include <hip/hip_bf16.h>
#include <math.h>

typedef __bf16 bf16_t;
typedef __bf16 bf16x8 __attribute__((ext_vector_type(8)));
typedef float f32x4 __attribute__((ext_vector_type(4)));

#define AS1q __attribute__((address_space(1)))
#define AS3q __attribute__((address_space(3)))

// async global->LDS, 16B per lane; LDS dest = wave-uniform base + lane*16
__device__ __forceinline__ void gload_lds16(const bf16_t* g, bf16_t* l) {
    __builtin_amdgcn_global_load_lds((AS1q void*)g, (AS3q void*)l, 16, 0, 0);
}

// ------------------------------------------------------------------
// constants for this problem (B=1, H=W=T=48, C=96, nh=3, hd=32)
// ------------------------------------------------------------------
#define LROWS   110592        // H*W*T
#define CDIM    96
#define NTOK    2304          // H*W
#define FDIM    1536          // B_*hd
#define YSTR    3538944ll     // 2304*1536 (per-g stride in Y)
#define SSTR    5308416ll     // 2304*2304
#define SCALE_Q 0.1767766952966369f   // 32^-0.5

// ------------------------------------------------------------------
// weight fp32 -> bf16 (qkv 27648 | proj 9216 | fc1 36864 | fc2 36864)
// ------------------------------------------------------------------
__global__ __launch_bounds__(256)
void conv_w(const float* __restrict__ a, const float* __restrict__ b,
            const float* __restrict__ c, const float* __restrict__ d,
            bf16_t* __restrict__ out)
{
    int i = blockIdx.x * 256 + threadIdx.x;   // 110592 total
    float v;
    if (i < 27648)       v = a[i];
    else if (i < 36864)  v = b[i - 27648];
    else if (i < 73728)  v = c[i - 36864];
    else                 v = d[i - 73728];
    out[i] = (bf16_t)v;
}

// ------------------------------------------------------------------
// LayerNorm over C=96, one wave per row; optional axial permute on output:
// src row l = n*48 + t  ->  dst row t*2304 + n
// ------------------------------------------------------------------
__global__ __launch_bounds__(256)
void ln_kernel(const float* __restrict__ x, const float* __restrict__ gamma,
               const float* __restrict__ beta, bf16_t* __restrict__ out, int permute)
{
    int wave = threadIdx.x >> 6, lane = threadIdx.x & 63;
    int row = blockIdx.x * 4 + wave;
    const float* xr = x + (size_t)row * CDIM;
    float e0 = xr[lane];
    float e1 = (lane < 32) ? xr[64 + lane] : 0.f;
    float s = e0 + e1;
    for (int off = 32; off > 0; off >>= 1) s += __shfl_xor(s, off, 64);
    float mean = s * (1.f / 96.f);
    float d0 = e0 - mean;
    float d1 = (lane < 32) ? (e1 - mean) : 0.f;
    float vs = d0 * d0 + d1 * d1;
    for (int off = 32; off > 0; off >>= 1) vs += __shfl_xor(vs, off, 64);
    float rstd = rsqrtf(vs * (1.f / 96.f) + 1e-5f);
    size_t orow = row;
    if (permute) { int t = row % 48; int n = row / 48; orow = (size_t)t * NTOK + n; }
    bf16_t* o = out + orow * CDIM;
    o[lane] = (bf16_t)(d0 * rstd * gamma[lane] + beta[lane]);
    if (lane < 32) o[64 + lane] = (bf16_t)(d1 * rstd * gamma[64 + lane] + beta[64 + lane]);
}

// ------------------------------------------------------------------
// V transpose: Y[6+z][n][m] -> Yv[z][m][n]   (64x64 LDS tiles)
// ------------------------------------------------------------------
__global__ __launch_bounds__(256)
void transpose_v(const bf16_t* __restrict__ Y, bf16_t* __restrict__ Yv)
{
    __shared__ bf16_t tile[64][65];
    const bf16_t* src = Y + (size_t)(6 + blockIdx.z) * YSTR;
    bf16_t* dst = Yv + (size_t)blockIdx.z * YSTR;
    int m0 = blockIdx.x * 64, n0 = blockIdx.y * 64;
    int nl = threadIdx.x >> 2, ch = threadIdx.x & 3;
    const bf16x8* s8 = (const bf16x8*)(src + (size_t)(n0 + nl) * FDIM + m0 + ch * 16);
    bf16x8 va = s8[0], vb = s8[1];
    #pragma unroll
    for (int j = 0; j < 8; j++) tile[nl][ch * 16 + j] = va[j];
    #pragma unroll
    for (int j = 0; j < 8; j++) tile[nl][ch * 16 + 8 + j] = vb[j];
    __syncthreads();
    bf16_t* d = dst + (size_t)(m0 + nl) * NTOK + n0 + ch * 16;
    #pragma unroll
    for (int j = 0; j < 16; j++) d[j] = tile[ch * 16 + j][nl];
}

// ------------------------------------------------------------------
// row softmax over 2304: S (f32) -> P (bf16).  One block (256 thr) per row.
// ------------------------------------------------------------------
__global__ __launch_bounds__(256)
void softmax_k(const float* __restrict__ S, bf16_t* __restrict__ P,
               long long sZ, long long pZ)
{
    __shared__ float red[8];
    const float* sr = S + (size_t)blockIdx.z * sZ + (size_t)blockIdx.x * NTOK;
    bf16_t* pr = P + (size_t)blockIdx.z * pZ + (size_t)blockIdx.x * NTOK;
    int wave = threadIdx.x >> 6, lane = threadIdx.x & 63;
    float v[9];
    float mx = -1e30f;
    #pragma unroll
    for (int t = 0; t < 9; t++) { v[t] = sr[t * 256 + threadIdx.x]; mx = fmaxf(mx, v[t]); }
    for (int off = 32; off > 0; off >>= 1) mx = fmaxf(mx, __shfl_xor(mx, off, 64));
    if (lane == 0) red[wave] = mx;
    __syncthreads();
    mx = fmaxf(fmaxf(red[0], red[1]), fmaxf(red[2], red[3]));
    float sum = 0.f;
    #pragma unroll
    for (int t = 0; t < 9; t++) { v[t] = __expf(v[t] - mx); sum += v[t]; }
    for (int off = 32; off > 0; off >>= 1) sum += __shfl_xor(sum, off, 64);
    if (lane == 0) red[4 + wave] = sum;
    __syncthreads();
    sum = red[4] + red[5] + red[6] + red[7];
    float inv = 1.f / sum;
    #pragma unroll
    for (int t = 0; t < 9; t++) pr[t * 256 + threadIdx.x] = (bf16_t)(v[t] * inv);
}

// ------------------------------------------------------------------
// bf16 MFMA GEMM (attention):  C[M,N] = A[M,K] @ W[N,K]^T
// BM=128, BK=32, 256 threads (2x2 waves, each 64 x BN/2).
// XOR swizzle (r>>1)&3 -> 2-way LDS aliasing (free; verified 0 conflicts R2).
// EPI: 1=S f32 (*scale)   2=PV scatter (o_rows)
// ------------------------------------------------------------------
template<int BM, int BN, int EPI>
__global__ __launch_bounds__(256, 2)
void gemm_bt(const bf16_t* __restrict__ A, const bf16_t* __restrict__ W,
             void* __restrict__ out, int K,
             long long aZ, long long wZ, long long oZ, float scale, int head0)
{
    constexpr int BK = 32;
    constexpr int WM = (BM == 128) ? 2 : 1;
    constexpr int WN = 4 / WM;
    constexpr int MI = BM / (WM * 16);
    constexpr int NT = BN / (WN * 16);
    __shared__ bf16_t As[BM * BK];
    __shared__ bf16_t Bs[BN * BK];

    const int tid = threadIdx.x;
    const int wave = tid >> 6, lane = tid & 63;
    const int quad = lane >> 4, l16 = lane & 15;
    const int wm = (WM == 2) ? (wave & 1) : 0;
    const int wn = (WM == 2) ? (wave >> 1) : wave;
    const int z = blockIdx.z;
    A += (size_t)z * aZ;
    W += (size_t)z * wZ;
    const int m0 = blockIdx.x * BM, n0 = blockIdx.y * BN;

    f32x4 acc[MI][NT];
    #pragma unroll
    for (int i = 0; i < MI; i++)
        #pragma unroll
        for (int j = 0; j < NT; j++) { f32x4 zz = {0.f, 0.f, 0.f, 0.f}; acc[i][j] = zz; }

    const int srow = lane >> 2;
    const int scol = lane & 3;

    for (int k0 = 0; k0 < K; k0 += BK) {
        __syncthreads();
        for (int it = wave; it < BM / 16; it += 4) {
            int r = it * 16 + srow;
            int cg = scol ^ ((r >> 1) & 3);
            gload_lds16(A + (size_t)(m0 + r) * K + k0 + cg * 8, &As[it * 512]);
        }
        for (int it = wave; it < BN / 16; it += 4) {
            int r = it * 16 + srow;
            int cg = scol ^ ((r >> 1) & 3);
            gload_lds16(W + (size_t)(n0 + r) * K + k0 + cg * 8, &Bs[it * 512]);
        }
        __syncthreads();

        bf16x8 af[MI], bfr[NT];
        #pragma unroll
        for (int i = 0; i < MI; i++) {
            int r = wm * 64 + i * 16 + l16;
            af[i] = *(const bf16x8*)&As[r * 32 + ((quad ^ ((r >> 1) & 3)) << 3)];
        }
        #pragma unroll
        for (int j = 0; j < NT; j++) {
            int c = wn * (BN / WN) + j * 16 + l16;
            bfr[j] = *(const bf16x8*)&Bs[c * 32 + ((quad ^ ((c >> 1) & 3)) << 3)];
        }
        #pragma unroll
        for (int i = 0; i < MI; i++)
            #pragma unroll
            for (int j = 0; j < NT; j++)
                acc[i][j] = __builtin_amdgcn_mfma_f32_16x16x32_bf16(af[i], bfr[j], acc[i][j], 0, 0, 0);
    }

    #pragma unroll
    for (int i = 0; i < MI; i++)
        #pragma unroll
        for (int j = 0; j < NT; j++)
            #pragma unroll
            for (int ri = 0; ri < 4; ri++) {
                int r = m0 + wm * 64 + i * 16 + quad * 4 + ri;
                int c = n0 + wn * (BN / WN) + j * 16 + l16;
                float v = acc[i][j][ri];
                if constexpr (EPI == 1) {
                    float* op = (float*)out + (size_t)z * oZ;
                    op[(size_t)r * NTOK + c] = v * scale;
                } else {
                    int h = head0 + z;
                    int b = r / 48, rr = r - b * 48;
                    ((bf16_t*)out)[((size_t)(b * NTOK + rr * 48 + h * 16)) * CDIM + c] = (bf16_t)v;
                }
            }
}

// ------------------------------------------------------------------
// Weight-resident GEMM:  C[M,N] = A[M,K] @ W[N,K]^T, W entirely in LDS.
// Block = 256 thr = 4 waves, BM=256 (64 rows/wave, MI=4). ONE barrier total:
// after W staging. K-loop is barrier-free: A streamed global->VGPR frags
// (16 rows x 64B contiguous per load), B from LDS (row stride K+8 elems
// -> bank starts cover all even banks -> <=2-way aliasing = free).
// KC = K-chunk held in registers. KC==K: A-resident, acc transient per
// n-tile (N can be large). KC<K: acc[4][N/16] persistent, A chunked.
// EPI: 0=QKV scatter(+bias) bf16   3=bias+GELU bf16   4=bias+residual f32
// ------------------------------------------------------------------
template<int N, int K, int KC, int EPI>
__global__ __launch_bounds__(256, 2)
void gemm_ws(const bf16_t* __restrict__ A, const bf16_t* __restrict__ Wg,
             void* __restrict__ out, const float* __restrict__ bias,
             const float* __restrict__ resid)
{
    constexpr int KP = K + 8;
    constexpr int NT = N / 16;
    constexpr int KI = KC / 32;
    __shared__ __attribute__((aligned(16))) bf16_t Ws[N * KP];

    const int tid = threadIdx.x;
    const int wave = tid >> 6, lane = tid & 63;
    const int quad = lane >> 4, l16 = lane & 15;
    const int m0 = blockIdx.x * 256;

    // stage W once (coalesced dwordx4 -> ds_write_b128)
    constexpr int CH = N * K / 8;
    for (int c = tid; c < CH; c += 256) {
        int row = c / (K / 8), kc = c - row * (K / 8);
        bf16x8 w = *(const bf16x8*)(Wg + row * K + kc * 8);
        *(bf16x8*)(Ws + row * KP + kc * 8) = w;
    }
    __syncthreads();

    const bf16_t* Ar = A + (size_t)(m0 + wave * 64 + l16) * K + quad * 8;

    // epilogue helper consts (EPI 0)
    const int t = m0 / NTOK;
    const int nb = m0 - t * NTOK;

    auto epi_tile = [&](int nt, const f32x4* a4) {
        int c = nt * 16 + l16;
        if constexpr (EPI == 0) {
            int jj = t * 288 + c;
            int g = jj / FDIM, mm = jj - g * FDIM;
            float bv = bias[c];
            bf16_t* yp = (bf16_t*)out + (size_t)g * YSTR + mm;
            #pragma unroll
            for (int i = 0; i < 4; i++)
                #pragma unroll
                for (int ri = 0; ri < 4; ri++) {
                    int n = nb + wave * 64 + i * 16 + quad * 4 + ri;
                    yp[(size_t)n * FDIM] = (bf16_t)(a4[i][ri] + bv);
                }
        } else {
            float bv = bias[c];
            #pragma unroll
            for (int i = 0; i < 4; i++)
                #pragma unroll
                for (int ri = 0; ri < 4; ri++) {
                    int r = m0 + wave * 64 + i * 16 + quad * 4 + ri;
                    float v = a4[i][ri] + bv;
                    if constexpr (EPI == 3) {
                        v = 0.5f * v * (1.0f + erff(v * 0.70710678118654752f));
                        ((bf16_t*)out)[(size_t)r * N + c] = (bf16_t)v;
                    } else {
                        ((float*)out)[(size_t)r * N + c] = v + resid[(size_t)r * N + c];
                    }
                }
        }
    };

    if constexpr (KC == K) {
        // A-resident: all A frags in regs, loop n-tiles with transient acc
        bf16x8 af[4][KI];
        #pragma unroll
        for (int i = 0; i < 4; i++)
            #pragma unroll
            for (int kk = 0; kk < KI; kk++)
                af[i][kk] = *(const bf16x8*)(Ar + (size_t)i * 16 * K + kk * 32);
        #pragma unroll 2
        for (int nt = 0; nt < NT; nt++) {
            bf16x8 bfr[KI];
            #pragma unroll
            for (int kk = 0; kk < KI; kk++)
                bfr[kk] = *(const bf16x8*)(Ws + (nt * 16 + l16) * KP + kk * 32 + quad * 8);
            f32x4 a4[4];
            #pragma unroll
            for (int i = 0; i < 4; i++) { f32x4 zz = {0.f, 0.f, 0.f, 0.f}; a4[i] = zz; }
            #pragma unroll
            for (int kk = 0; kk < KI; kk++)
                #pragma unroll
                for (int i = 0; i < 4; i++)
                    a4[i] = __builtin_amdgcn_mfma_f32_16x16x32_bf16(af[i][kk], bfr[kk], a4[i], 0, 0, 0);
            epi_tile(nt, a4);
        }
    } else {
        // acc-resident: persistent acc over all n-tiles, A chunked by KC
        f32x4 acc[4][NT];
        #pragma unroll
        for (int i = 0; i < 4; i++)
            #pragma unroll
            for (int j = 0; j < NT; j++) { f32x4 zz = {0.f, 0.f, 0.f, 0.f}; acc[i][j] = zz; }
        for (int kc0 = 0; kc0 < K; kc0 += KC) {
            bf16x8 af[4][KI];
            #pragma unroll
            for (int i = 0; i < 4; i++)
                #pragma unroll
                for (int kk = 0; kk < KI; kk++)
                    af[i][kk] = *(const bf16x8*)(Ar + (size_t)i * 16 * K + kc0 + kk * 32);
            #pragma unroll
            for (int nt = 0; nt < NT; nt++) {
                #pragma unroll
                for (int kk = 0; kk < KI; kk++) {
                    bf16x8 b = *(const bf16x8*)(Ws + (nt * 16 + l16) * KP + kc0 + kk * 32 + quad * 8);
                    acc[nt & 3][nt] = acc[nt & 3][nt]; // no-op keeps indexing simple
                    #pragma unroll
                    for (int i = 0; i < 4; i++)
                        acc[i][nt] = __builtin_amdgcn_mfma_f32_16x16x32_bf16(af[i][kk], b, acc[i][nt], 0, 0, 0);
                }
            }
        }
        #pragma unroll
        for (int nt = 0; nt < NT; nt++) {
            f32x4 a4[4];
            #pragma unroll
            for (int i = 0; i < 4; i++) a4[i] = acc[i][nt];
            epi_tile(nt, a4);
        }
    }
}

// ------------------------------------------------------------------
extern "C" void kernel_launch(void* const* d_in, const int* in_sizes, int n_in,
                              void* d_out, int out_size, void* d_ws, size_t ws_size,
                              hipStream_t stream)
{
    const float* x      = (const float*)d_in[0];
    const float* ln1_g  = (const float*)d_in[2];
    const float* ln1_b  = (const float*)d_in[3];
    const float* qkv_w  = (const float*)d_in[4];
    const float* qkv_b  = (const float*)d_in[5];
    const float* proj_w = (const float*)d_in[6];
    const float* proj_b = (const float*)d_in[7];
    const float* ln2_g  = (const float*)d_in[8];
    const float* ln2_b  = (const float*)d_in[9];
    const float* fc1_w  = (const float*)d_in[10];
    const float* fc1_b  = (const float*)d_in[11];
    const float* fc2_w  = (const float*)d_in[12];
    const float* fc2_b  = (const float*)d_in[13];

    // ---- workspace layout ----
    const size_t SZ_WB = 110592ull * 2;          // bf16 weights
    const size_t SZ_HP = 10616832ull * 2;        // hp / o_rows / h2
    const size_t SZ_Y  = 31850496ull * 2;        // Y [9][2304][1536]
    const size_t SZ_YV = 10616832ull * 2;        // Yv [3][1536][2304]
    const size_t SZ_S1 = 5308416ull * 4;         // S per head (f32)
    const size_t SZ_P1 = 5308416ull * 2;         // P per head (bf16)
    const size_t SZ_X2 = 10616832ull * 4;        // x2 (f32)

    char* ws = (char*)d_ws;
    size_t oWB = 0;
    size_t oHP = oWB + SZ_WB;
    size_t oY  = oHP + SZ_HP;
    size_t oYV = oY + SZ_Y;
    size_t oS  = oYV + SZ_YV;
    size_t needBig   = oS + 3 * SZ_S1 + 3 * SZ_P1 + SZ_X2;
    bool big = (ws_size >= needBig);
    size_t oP  = oS + (big ? 3 * SZ_S1 : SZ_S1);
    size_t oX2 = oP + (big ? 3 * SZ_P1 : SZ_P1);

    bf16_t* Wb    = (bf16_t*)(ws + oWB);
    bf16_t* Wqkv  = Wb;
    bf16_t* Wproj = Wb + 27648;
    bf16_t* Wfc1  = Wb + 36864;
    bf16_t* Wfc2  = Wb + 73728;
    bf16_t* hp    = (bf16_t*)(ws + oHP);   // then o_rows, then h2
    bf16_t* Y     = (bf16_t*)(ws + oY);
    bf16_t* Yv    = (bf16_t*)(ws + oYV);
    bf16_t* t1    = (bf16_t*)(ws + oY);    // reuses Y+Yv (exact fit)
    float*  Sb    = (float*)(ws + oS);
    bf16_t* Pb    = (bf16_t*)(ws + oP);
    float*  x2    = (float*)(ws + oX2);
    float*  outp  = (float*)d_out;

    dim3 blk(256);

    // 1. weights -> bf16
    conv_w<<<dim3(432), blk, 0, stream>>>(qkv_w, proj_w, fc1_w, fc2_w, Wb);
    // 2. LN1 + axial permute -> hp [48][2304][96]
    ln_kernel<<<dim3(27648), blk, 0, stream>>>(x, ln1_g, ln1_b, hp, 1);
    // 3. QKV gemm (W-resident, barrier-free K) -> Y scattered
    gemm_ws<288, 96, 96, 0><<<dim3(432), blk, 0, stream>>>(hp, Wqkv, Y, qkv_b, nullptr);
    // 4. V transpose -> Yv [h][m][n]
    transpose_v<<<dim3(24, 36, 3), blk, 0, stream>>>(Y, Yv);

    // 5-7. attention (BM=128: 16 MFMA per barrier-pair; swizzle => 0 conflicts)
    if (big) {
        gemm_bt<128, 128, 1><<<dim3(18, 18, 3), blk, 0, stream>>>(Y, Y + 3 * YSTR, Sb,
                                                                  1536, YSTR, YSTR, SSTR, SCALE_Q, 0);
        softmax_k<<<dim3(2304, 1, 3), blk, 0, stream>>>(Sb, Pb, SSTR, SSTR);
        gemm_bt<128, 128, 2><<<dim3(18, 12, 3), blk, 0, stream>>>(Pb, Yv, hp,
                                                                  2304, SSTR, YSTR, 0, 0.f, 0);
    } else {
        for (int h = 0; h < 3; h++) {
            gemm_bt<128, 128, 1><<<dim3(18, 18, 1), blk, 0, stream>>>(Y + (size_t)h * YSTR, Y + (size_t)(3 + h) * YSTR,
                                                                      Sb, 1536, 0, 0, 0, SCALE_Q, 0);
            softmax_k<<<dim3(2304, 1, 1), blk, 0, stream>>>(Sb, Pb, 0, 0);
            gemm_bt<128, 128, 2><<<dim3(18, 12, 1), blk, 0, stream>>>(Pb, Yv + (size_t)h * YSTR, hp,
                                                                      2304, 0, 0, 0, 0.f, h);
        }
    }

    // 8. proj + residual -> x2 (f32)
    gemm_ws<96, 96, 96, 4><<<dim3(432), blk, 0, stream>>>(hp, Wproj, x2, proj_b, x);
    // 9. LN2 -> h2 (reuses hp region)
    ln_kernel<<<dim3(27648), blk, 0, stream>>>(x2, ln2_g, ln2_b, hp, 0);
    // 10. fc1 + GELU -> t1 (reuses Y+Yv region)
    gemm_ws<384, 96, 96, 3><<<dim3(432), blk, 0, stream>>>(hp, Wfc1, t1, fc1_b, nullptr);
    // 11. fc2 + residual -> out (f32; acc-resident, KC=96)
    gemm_ws<96, 384, 96, 4><<<dim3(432), blk, 0, stream>>>(t1, Wfc2, outp, fc2_b, x2);
}

// Round 4
// 453.131 us; speedup vs baseline: 1.1326x; 1.0757x over previous
//
#include <hip/hip_runtime.h>
#include <hip/hip_bf16.h>
#include <math.h>

typedef __bf16 bf16_t;
typedef __bf16 bf16x8 __attribute__((ext_vector_type(8)));
typedef float f32x4 __attribute__((ext_vector_type(4)));

#define AS1q __attribute__((address_space(1)))
#define AS3q __attribute__((address_space(3)))

// async global->LDS, 16B per lane; LDS dest = wave-uniform base + lane*16
__device__ __forceinline__ void gload_lds16(const bf16_t* g, bf16_t* l) {
    __builtin_amdgcn_global_load_lds((AS1q void*)g, (AS3q void*)l, 16, 0, 0);
}

// ------------------------------------------------------------------
// constants for this problem (B=1, H=W=T=48, C=96, nh=3, hd=32)
// ------------------------------------------------------------------
#define LROWS   110592        // H*W*T
#define CDIM    96
#define NTOK    2304          // H*W
#define FDIM    1536          // B_*hd
#define YSTR    3538944ll     // 2304*1536 (per-g stride in Y)
#define SSTR    5308416ll     // 2304*2304
#define SCALE_Q 0.1767766952966369f   // 32^-0.5

// ------------------------------------------------------------------
// weight fp32 -> bf16 (qkv 27648 | proj 9216 | fc1 36864 | fc2 36864)
// ------------------------------------------------------------------
__global__ __launch_bounds__(256)
void conv_w(const float* __restrict__ a, const float* __restrict__ b,
            const float* __restrict__ c, const float* __restrict__ d,
            bf16_t* __restrict__ out)
{
    int i = blockIdx.x * 256 + threadIdx.x;   // 110592 total
    float v;
    if (i < 27648)       v = a[i];
    else if (i < 36864)  v = b[i - 27648];
    else if (i < 73728)  v = c[i - 36864];
    else                 v = d[i - 73728];
    out[i] = (bf16_t)v;
}

// ------------------------------------------------------------------
// LayerNorm over C=96, one wave per row; optional axial permute on output:
// src row l = n*48 + t  ->  dst row t*2304 + n
// ------------------------------------------------------------------
__global__ __launch_bounds__(256)
void ln_kernel(const float* __restrict__ x, const float* __restrict__ gamma,
               const float* __restrict__ beta, bf16_t* __restrict__ out, int permute)
{
    int wave = threadIdx.x >> 6, lane = threadIdx.x & 63;
    int row = blockIdx.x * 4 + wave;
    const float* xr = x + (size_t)row * CDIM;
    float e0 = xr[lane];
    float e1 = (lane < 32) ? xr[64 + lane] : 0.f;
    float s = e0 + e1;
    for (int off = 32; off > 0; off >>= 1) s += __shfl_xor(s, off, 64);
    float mean = s * (1.f / 96.f);
    float d0 = e0 - mean;
    float d1 = (lane < 32) ? (e1 - mean) : 0.f;
    float vs = d0 * d0 + d1 * d1;
    for (int off = 32; off > 0; off >>= 1) vs += __shfl_xor(vs, off, 64);
    float rstd = rsqrtf(vs * (1.f / 96.f) + 1e-5f);
    size_t orow = row;
    if (permute) { int t = row % 48; int n = row / 48; orow = (size_t)t * NTOK + n; }
    bf16_t* o = out + orow * CDIM;
    o[lane] = (bf16_t)(d0 * rstd * gamma[lane] + beta[lane]);
    if (lane < 32) o[64 + lane] = (bf16_t)(d1 * rstd * gamma[64 + lane] + beta[64 + lane]);
}

// ------------------------------------------------------------------
// V transpose: Y[6+z][n][m] -> Yv[z][m][n]   (64x64 LDS tiles)
// ------------------------------------------------------------------
__global__ __launch_bounds__(256)
void transpose_v(const bf16_t* __restrict__ Y, bf16_t* __restrict__ Yv)
{
    __shared__ bf16_t tile[64][65];
    const bf16_t* src = Y + (size_t)(6 + blockIdx.z) * YSTR;
    bf16_t* dst = Yv + (size_t)blockIdx.z * YSTR;
    int m0 = blockIdx.x * 64, n0 = blockIdx.y * 64;
    int nl = threadIdx.x >> 2, ch = threadIdx.x & 3;
    const bf16x8* s8 = (const bf16x8*)(src + (size_t)(n0 + nl) * FDIM + m0 + ch * 16);
    bf16x8 va = s8[0], vb = s8[1];
    #pragma unroll
    for (int j = 0; j < 8; j++) tile[nl][ch * 16 + j] = va[j];
    #pragma unroll
    for (int j = 0; j < 8; j++) tile[nl][ch * 16 + 8 + j] = vb[j];
    __syncthreads();
    bf16_t* d = dst + (size_t)(m0 + nl) * NTOK + n0 + ch * 16;
    #pragma unroll
    for (int j = 0; j < 16; j++) d[j] = tile[ch * 16 + j][nl];
}

// ------------------------------------------------------------------
// row softmax over 2304: S (f32) -> P (bf16).  One block (256 thr) per row.
// ------------------------------------------------------------------
__global__ __launch_bounds__(256)
void softmax_k(const float* __restrict__ S, bf16_t* __restrict__ P,
               long long sZ, long long pZ)
{
    __shared__ float red[8];
    const float* sr = S + (size_t)blockIdx.z * sZ + (size_t)blockIdx.x * NTOK;
    bf16_t* pr = P + (size_t)blockIdx.z * pZ + (size_t)blockIdx.x * NTOK;
    int wave = threadIdx.x >> 6, lane = threadIdx.x & 63;
    float v[9];
    float mx = -1e30f;
    #pragma unroll
    for (int t = 0; t < 9; t++) { v[t] = sr[t * 256 + threadIdx.x]; mx = fmaxf(mx, v[t]); }
    for (int off = 32; off > 0; off >>= 1) mx = fmaxf(mx, __shfl_xor(mx, off, 64));
    if (lane == 0) red[wave] = mx;
    __syncthreads();
    mx = fmaxf(fmaxf(red[0], red[1]), fmaxf(red[2], red[3]));
    float sum = 0.f;
    #pragma unroll
    for (int t = 0; t < 9; t++) { v[t] = __expf(v[t] - mx); sum += v[t]; }
    for (int off = 32; off > 0; off >>= 1) sum += __shfl_xor(sum, off, 64);
    if (lane == 0) red[4 + wave] = sum;
    __syncthreads();
    sum = red[4] + red[5] + red[6] + red[7];
    float inv = 1.f / sum;
    #pragma unroll
    for (int t = 0; t < 9; t++) pr[t * 256 + threadIdx.x] = (bf16_t)(v[t] * inv);
}

// ------------------------------------------------------------------
// bf16 MFMA GEMM (attention):  C[M,N] = A[M,K] @ W[N,K]^T
// BM=128, BK=32, 256 threads (2x2 waves, each 64 x BN/2).
// XOR swizzle (r>>1)&3 -> 2-way LDS aliasing (verified 0 conflicts R2/R3).
// XCD/L2 block swizzle: (id&7)*chunk+(id>>3) gives each XCD a contiguous
// id2 range; id2 mapped through 6-wide column panels so each XCD's chunk
// covers ~7 M-tiles x 6 N-tiles (~5 MB of A+B ~ its 4 MiB L2).
// M-tiles fixed at 18 (2304/128). NBY = N-tiles (18 for S, 12 for PV).
// EPI: 1=S f32 (*scale)   2=PV scatter (o_rows)
// ------------------------------------------------------------------
template<int BN, int EPI, int NBY>
__global__ __launch_bounds__(256, 2)
void gemm_bt(const bf16_t* __restrict__ A, const bf16_t* __restrict__ W,
             void* __restrict__ out, int K,
             long long aZ, long long wZ, long long oZ, float scale)
{
    constexpr int BM = 128, BK = 32;
    constexpr int MI = 4;                 // m-tiles per wave
    constexpr int NT = BN / 32;           // n-tiles per wave
    constexpr int NB = 18 * NBY;
    constexpr int CHK = (NB + 7) / 8;
    __shared__ bf16_t As[BM * BK];
    __shared__ bf16_t Bs[BN * BK];

    // XCD-contiguous + panel mapping
    int id = blockIdx.x;
    int id2 = (id & 7) * CHK + (id >> 3);
    if (id2 >= NB) return;
    int p  = id2 / 108;                   // panel of 6 n-columns (18*6=108)
    int r_ = id2 - p * 108;
    int by = p * 6 + (r_ % 6);
    int bx = r_ / 6;

    const int tid = threadIdx.x;
    const int wave = tid >> 6, lane = tid & 63;
    const int quad = lane >> 4, l16 = lane & 15;
    const int wm = wave & 1, wn = wave >> 1;
    const int z = blockIdx.z;
    A += (size_t)z * aZ;
    W += (size_t)z * wZ;
    const int m0 = bx * BM, n0 = by * BN;

    f32x4 acc[MI][NT];
    #pragma unroll
    for (int i = 0; i < MI; i++)
        #pragma unroll
        for (int j = 0; j < NT; j++) { f32x4 zz = {0.f, 0.f, 0.f, 0.f}; acc[i][j] = zz; }

    const int srow = lane >> 2;
    const int scol = lane & 3;

    for (int k0 = 0; k0 < K; k0 += BK) {
        __syncthreads();
        for (int it = wave; it < BM / 16; it += 4) {
            int r = it * 16 + srow;
            int cg = scol ^ ((r >> 1) & 3);
            gload_lds16(A + (size_t)(m0 + r) * K + k0 + cg * 8, &As[it * 512]);
        }
        for (int it = wave; it < BN / 16; it += 4) {
            int r = it * 16 + srow;
            int cg = scol ^ ((r >> 1) & 3);
            gload_lds16(W + (size_t)(n0 + r) * K + k0 + cg * 8, &Bs[it * 512]);
        }
        __syncthreads();

        bf16x8 af[MI], bfr[NT];
        #pragma unroll
        for (int i = 0; i < MI; i++) {
            int r = wm * 64 + i * 16 + l16;
            af[i] = *(const bf16x8*)&As[r * 32 + ((quad ^ ((r >> 1) & 3)) << 3)];
        }
        #pragma unroll
        for (int j = 0; j < NT; j++) {
            int c = wn * (BN / 2) + j * 16 + l16;
            bfr[j] = *(const bf16x8*)&Bs[c * 32 + ((quad ^ ((c >> 1) & 3)) << 3)];
        }
        #pragma unroll
        for (int i = 0; i < MI; i++)
            #pragma unroll
            for (int j = 0; j < NT; j++)
                acc[i][j] = __builtin_amdgcn_mfma_f32_16x16x32_bf16(af[i], bfr[j], acc[i][j], 0, 0, 0);
    }

    #pragma unroll
    for (int i = 0; i < MI; i++)
        #pragma unroll
        for (int j = 0; j < NT; j++)
            #pragma unroll
            for (int ri = 0; ri < 4; ri++) {
                int r = m0 + wm * 64 + i * 16 + quad * 4 + ri;
                int c = n0 + wn * (BN / 2) + j * 16 + l16;
                float v = acc[i][j][ri];
                if constexpr (EPI == 1) {
                    float* op = (float*)out + (size_t)z * oZ;
                    op[(size_t)r * NTOK + c] = v * scale;
                } else {
                    int b = r / 48, rr = r - b * 48;
                    ((bf16_t*)out)[((size_t)(b * NTOK + rr * 48 + z * 16)) * CDIM + c] = (bf16_t)v;
                }
            }
}

// ------------------------------------------------------------------
// Weight-resident GEMM:  C[M,N] = A[M,K] @ W[N,K]^T, W entirely in LDS.
// Block = 256 thr = 4 waves, BM=256 (64 rows/wave, MI=4). ONE barrier total.
// EPI: 0=QKV scatter(+bias) bf16   3=bias+GELU bf16   4=bias+residual f32
// ------------------------------------------------------------------
template<int N, int K, int KC, int EPI>
__global__ __launch_bounds__(256, 2)
void gemm_ws(const bf16_t* __restrict__ A, const bf16_t* __restrict__ Wg,
             void* __restrict__ out, const float* __restrict__ bias,
             const float* __restrict__ resid)
{
    constexpr int KP = K + 8;
    constexpr int NT = N / 16;
    constexpr int KI = KC / 32;
    __shared__ __attribute__((aligned(16))) bf16_t Ws[N * KP];

    const int tid = threadIdx.x;
    const int wave = tid >> 6, lane = tid & 63;
    const int quad = lane >> 4, l16 = lane & 15;
    const int m0 = blockIdx.x * 256;

    // stage W once (coalesced dwordx4 -> ds_write_b128)
    constexpr int CH = N * K / 8;
    for (int c = tid; c < CH; c += 256) {
        int row = c / (K / 8), kc = c - row * (K / 8);
        bf16x8 w = *(const bf16x8*)(Wg + row * K + kc * 8);
        *(bf16x8*)(Ws + row * KP + kc * 8) = w;
    }
    __syncthreads();

    const bf16_t* Ar = A + (size_t)(m0 + wave * 64 + l16) * K + quad * 8;

    const int t = m0 / NTOK;
    const int nb = m0 - t * NTOK;

    auto epi_tile = [&](int nt, const f32x4* a4) {
        int c = nt * 16 + l16;
        if constexpr (EPI == 0) {
            int jj = t * 288 + c;
            int g = jj / FDIM, mm = jj - g * FDIM;
            float bv = bias[c];
            bf16_t* yp = (bf16_t*)out + (size_t)g * YSTR + mm;
            #pragma unroll
            for (int i = 0; i < 4; i++)
                #pragma unroll
                for (int ri = 0; ri < 4; ri++) {
                    int n = nb + wave * 64 + i * 16 + quad * 4 + ri;
                    yp[(size_t)n * FDIM] = (bf16_t)(a4[i][ri] + bv);
                }
        } else {
            float bv = bias[c];
            #pragma unroll
            for (int i = 0; i < 4; i++)
                #pragma unroll
                for (int ri = 0; ri < 4; ri++) {
                    int r = m0 + wave * 64 + i * 16 + quad * 4 + ri;
                    float v = a4[i][ri] + bv;
                    if constexpr (EPI == 3) {
                        v = 0.5f * v * (1.0f + erff(v * 0.70710678118654752f));
                        ((bf16_t*)out)[(size_t)r * N + c] = (bf16_t)v;
                    } else {
                        ((float*)out)[(size_t)r * N + c] = v + resid[(size_t)r * N + c];
                    }
                }
        }
    };

    if constexpr (KC == K) {
        bf16x8 af[4][KI];
        #pragma unroll
        for (int i = 0; i < 4; i++)
            #pragma unroll
            for (int kk = 0; kk < KI; kk++)
                af[i][kk] = *(const bf16x8*)(Ar + (size_t)i * 16 * K + kk * 32);
        #pragma unroll 2
        for (int nt = 0; nt < NT; nt++) {
            bf16x8 bfr[KI];
            #pragma unroll
            for (int kk = 0; kk < KI; kk++)
                bfr[kk] = *(const bf16x8*)(Ws + (nt * 16 + l16) * KP + kk * 32 + quad * 8);
            f32x4 a4[4];
            #pragma unroll
            for (int i = 0; i < 4; i++) { f32x4 zz = {0.f, 0.f, 0.f, 0.f}; a4[i] = zz; }
            #pragma unroll
            for (int kk = 0; kk < KI; kk++)
                #pragma unroll
                for (int i = 0; i < 4; i++)
                    a4[i] = __builtin_amdgcn_mfma_f32_16x16x32_bf16(af[i][kk], bfr[kk], a4[i], 0, 0, 0);
            epi_tile(nt, a4);
        }
    } else {
        f32x4 acc[4][NT];
        #pragma unroll
        for (int i = 0; i < 4; i++)
            #pragma unroll
            for (int j = 0; j < NT; j++) { f32x4 zz = {0.f, 0.f, 0.f, 0.f}; acc[i][j] = zz; }
        for (int kc0 = 0; kc0 < K; kc0 += KC) {
            bf16x8 af[4][KI];
            #pragma unroll
            for (int i = 0; i < 4; i++)
                #pragma unroll
                for (int kk = 0; kk < KI; kk++)
                    af[i][kk] = *(const bf16x8*)(Ar + (size_t)i * 16 * K + kc0 + kk * 32);
            #pragma unroll
            for (int nt = 0; nt < NT; nt++) {
                #pragma unroll
                for (int kk = 0; kk < KI; kk++) {
                    bf16x8 b = *(const bf16x8*)(Ws + (nt * 16 + l16) * KP + kc0 + kk * 32 + quad * 8);
                    #pragma unroll
                    for (int i = 0; i < 4; i++)
                        acc[i][nt] = __builtin_amdgcn_mfma_f32_16x16x32_bf16(af[i][kk], b, acc[i][nt], 0, 0, 0);
                }
            }
        }
        #pragma unroll
        for (int nt = 0; nt < NT; nt++) {
            f32x4 a4[4];
            #pragma unroll
            for (int i = 0; i < 4; i++) a4[i] = acc[i][nt];
            epi_tile(nt, a4);
        }
    }
}

// ------------------------------------------------------------------
extern "C" void kernel_launch(void* const* d_in, const int* in_sizes, int n_in,
                              void* d_out, int out_size, void* d_ws, size_t ws_size,
                              hipStream_t stream)
{
    const float* x      = (const float*)d_in[0];
    const float* ln1_g  = (const float*)d_in[2];
    const float* ln1_b  = (const float*)d_in[3];
    const float* qkv_w  = (const float*)d_in[4];
    const float* qkv_b  = (const float*)d_in[5];
    const float* proj_w = (const float*)d_in[6];
    const float* proj_b = (const float*)d_in[7];
    const float* ln2_g  = (const float*)d_in[8];
    const float* ln2_b  = (const float*)d_in[9];
    const float* fc1_w  = (const float*)d_in[10];
    const float* fc1_b  = (const float*)d_in[11];
    const float* fc2_w  = (const float*)d_in[12];
    const float* fc2_b  = (const float*)d_in[13];

    // ---- workspace layout, 170.1 MB total (aliased by liveness) ----
    // [WB 0.2MB][HP 21.2MB][Y 63.7MB][YV 21.2MB][S 63.7MB]
    //  HP: ln1out (dead@QKV) -> o_rows (PV out, dead@proj) -> h2 (LN2 out)
    //  Y : QKV out (Q,K dead@S; V dead@transpose) -> P (softmax out, 31.9MB)
    //      -> t1 (fc1 out, 85MB = Y+YV, born after P/Yv dead)
    //  S : S f32 (dead@softmax) -> x2 (42.5MB, born@proj)
    const size_t SZ_WB = 110592ull * 2;
    const size_t SZ_HP = 10616832ull * 2;
    const size_t SZ_Y  = 31850496ull * 2;
    const size_t SZ_YV = 10616832ull * 2;

    char* ws = (char*)d_ws;
    size_t oWB = 0;
    size_t oHP = oWB + SZ_WB;
    size_t oY  = oHP + SZ_HP;
    size_t oYV = oY + SZ_Y;
    size_t oS  = oYV + SZ_YV;

    bf16_t* Wb    = (bf16_t*)(ws + oWB);
    bf16_t* Wqkv  = Wb;
    bf16_t* Wproj = Wb + 27648;
    bf16_t* Wfc1  = Wb + 36864;
    bf16_t* Wfc2  = Wb + 73728;
    bf16_t* hp    = (bf16_t*)(ws + oHP);   // ln1out / o_rows / h2
    bf16_t* Y     = (bf16_t*)(ws + oY);
    bf16_t* Yv    = (bf16_t*)(ws + oYV);
    bf16_t* Pb    = (bf16_t*)(ws + oY);    // P aliases Y (Q/K dead)
    bf16_t* t1    = (bf16_t*)(ws + oY);    // t1 aliases Y+YV
    float*  Sb    = (float*)(ws + oS);
    float*  x2    = (float*)(ws + oS);     // x2 aliases S (dead after softmax)
    float*  outp  = (float*)d_out;

    dim3 blk(256);

    // 1. weights -> bf16
    conv_w<<<dim3(432), blk, 0, stream>>>(qkv_w, proj_w, fc1_w, fc2_w, Wb);
    // 2. LN1 + axial permute -> hp [48][2304][96]
    ln_kernel<<<dim3(27648), blk, 0, stream>>>(x, ln1_g, ln1_b, hp, 1);
    // 3. QKV gemm (W-resident, barrier-free K) -> Y scattered
    gemm_ws<288, 96, 96, 0><<<dim3(432), blk, 0, stream>>>(hp, Wqkv, Y, qkv_b, nullptr);
    // 4. V transpose -> Yv [h][m][n]
    transpose_v<<<dim3(24, 36, 3), blk, 0, stream>>>(Y, Yv);

    // 5. S = Q@K^T (batched over heads; 328*8? grid = chunk*8 = 328)
    gemm_bt<128, 1, 18><<<dim3(328, 1, 3), blk, 0, stream>>>(Y, Y + 3 * YSTR, Sb,
                                                             1536, YSTR, YSTR, SSTR, SCALE_Q);
    // 6. softmax -> P (aliases Y; Q/K dead)
    softmax_k<<<dim3(2304, 1, 3), blk, 0, stream>>>(Sb, Pb, SSTR, SSTR);
    // 7. O = P@V^T -> o_rows in hp (grid 27*8 = 216 exact)
    gemm_bt<128, 2, 12><<<dim3(216, 1, 3), blk, 0, stream>>>(Pb, Yv, hp,
                                                             2304, SSTR, YSTR, 0, 0.f);

    // 8. proj + residual -> x2 (aliases S; S dead)
    gemm_ws<96, 96, 96, 4><<<dim3(432), blk, 0, stream>>>(hp, Wproj, x2, proj_b, x);
    // 9. LN2 -> h2 (reuses hp region)
    ln_kernel<<<dim3(27648), blk, 0, stream>>>(x2, ln2_g, ln2_b, hp, 0);
    // 10. fc1 + GELU -> t1 (aliases Y+YV; P and Yv dead)
    gemm_ws<384, 96, 96, 3><<<dim3(432), blk, 0, stream>>>(hp, Wfc1, t1, fc1_b, nullptr);
    // 11. fc2 + residual -> out (f32; acc-resident, KC=96)
    gemm_ws<96, 384, 96, 4><<<dim3(432), blk, 0, stream>>>(t1, Wfc2, outp, fc2_b, x2);
}

// Round 5
// 403.591 us; speedup vs baseline: 1.2716x; 1.1227x over previous
//
#include <hip/hip_runtime.h>
#include <hip/hip_bf16.h>
#include <math.h>

typedef __bf16 bf16_t;
typedef __bf16 bf16x8 __attribute__((ext_vector_type(8)));
typedef __bf16 bf16x4 __attribute__((ext_vector_type(4)));
typedef float f32x4 __attribute__((ext_vector_type(4)));

#define AS1q __attribute__((address_space(1)))
#define AS3q __attribute__((address_space(3)))

// async global->LDS, 16B per lane; LDS dest = wave-uniform base + lane*16
__device__ __forceinline__ void gload_lds16(const bf16_t* g, bf16_t* l) {
    __builtin_amdgcn_global_load_lds((AS1q void*)g, (AS3q void*)l, 16, 0, 0);
}

// ------------------------------------------------------------------
// constants (B=1, H=W=T=48, C=96, nh=3, hd=32)
// ------------------------------------------------------------------
#define LROWS   110592
#define CDIM    96
#define NTOK    2304
#define FDIM    1536
#define YSTR    3538944ll     // 2304*1536
#define SSTR    5308416ll     // 2304*2304
#define SCALE_Q 0.1767766952966369f

// ------------------------------------------------------------------
// weight fp32 -> bf16
// ------------------------------------------------------------------
__global__ __launch_bounds__(256)
void conv_w(const float* __restrict__ a, const float* __restrict__ b,
            const float* __restrict__ c, const float* __restrict__ d,
            bf16_t* __restrict__ out)
{
    int i = blockIdx.x * 256 + threadIdx.x;
    float v;
    if (i < 27648)       v = a[i];
    else if (i < 36864)  v = b[i - 27648];
    else if (i < 73728)  v = c[i - 36864];
    else                 v = d[i - 73728];
    out[i] = (bf16_t)v;
}

// ------------------------------------------------------------------
// Vectorized LayerNorm (float4 loads), 8 rows/block, 32 lanes/row.
// permute: src row l = n*48+t -> dst row t*2304+n
// ------------------------------------------------------------------
__global__ __launch_bounds__(256)
void ln4_kernel(const float* __restrict__ x, const float* __restrict__ gamma,
                const float* __restrict__ beta, bf16_t* __restrict__ out, int permute)
{
    int wave = threadIdx.x >> 6;
    int half = (threadIdx.x >> 5) & 1;
    int cl   = threadIdx.x & 31;          // chunk lane within row
    int row  = blockIdx.x * 8 + wave * 2 + half;
    bool act = cl < 24;                   // 24 float4 = 96 floats
    const f32x4* xr = (const f32x4*)(x + (size_t)row * CDIM);
    f32x4 v = {0.f, 0.f, 0.f, 0.f};
    if (act) v = xr[cl];
    float s = v[0] + v[1] + v[2] + v[3];
    #pragma unroll
    for (int off = 16; off > 0; off >>= 1) s += __shfl_xor(s, off, 64);
    float mean = s * (1.f / 96.f);
    f32x4 d = {0.f, 0.f, 0.f, 0.f};
    if (act) { d[0]=v[0]-mean; d[1]=v[1]-mean; d[2]=v[2]-mean; d[3]=v[3]-mean; }
    float vs = d[0]*d[0] + d[1]*d[1] + d[2]*d[2] + d[3]*d[3];
    #pragma unroll
    for (int off = 16; off > 0; off >>= 1) vs += __shfl_xor(vs, off, 64);
    float rstd = rsqrtf(vs * (1.f / 96.f) + 1e-5f);
    size_t orow = row;
    if (permute) { int t = row % 48; int n = row / 48; orow = (size_t)t * NTOK + n; }
    if (act) {
        f32x4 g = ((const f32x4*)gamma)[cl];
        f32x4 b = ((const f32x4*)beta)[cl];
        bf16x4 o;
        #pragma unroll
        for (int j = 0; j < 4; j++) o[j] = (bf16_t)(d[j] * rstd * g[j] + b[j]);
        *(bf16x4*)(out + orow * CDIM + cl * 4) = o;
    }
}

// ------------------------------------------------------------------
// V transpose: Y[6+z][n][m] -> Yv[z][m][n]
// ------------------------------------------------------------------
__global__ __launch_bounds__(256)
void transpose_v(const bf16_t* __restrict__ Y, bf16_t* __restrict__ Yv)
{
    __shared__ bf16_t tile[64][65];
    const bf16_t* src = Y + (size_t)(6 + blockIdx.z) * YSTR;
    bf16_t* dst = Yv + (size_t)blockIdx.z * YSTR;
    int m0 = blockIdx.x * 64, n0 = blockIdx.y * 64;
    int nl = threadIdx.x >> 2, ch = threadIdx.x & 3;
    const bf16x8* s8 = (const bf16x8*)(src + (size_t)(n0 + nl) * FDIM + m0 + ch * 16);
    bf16x8 va = s8[0], vb = s8[1];
    #pragma unroll
    for (int j = 0; j < 8; j++) tile[nl][ch * 16 + j] = va[j];
    #pragma unroll
    for (int j = 0; j < 8; j++) tile[nl][ch * 16 + 8 + j] = vb[j];
    __syncthreads();
    bf16_t* d = dst + (size_t)(m0 + nl) * NTOK + n0 + ch * 16;
    #pragma unroll
    for (int j = 0; j < 16; j++) d[j] = tile[ch * 16 + j][nl];
}

// ------------------------------------------------------------------
// row softmax over 2304: S (f32) -> P (bf16)
// ------------------------------------------------------------------
__global__ __launch_bounds__(256)
void softmax_k(const float* __restrict__ S, bf16_t* __restrict__ P,
               long long sZ, long long pZ)
{
    __shared__ float red[8];
    const float* sr = S + (size_t)blockIdx.z * sZ + (size_t)blockIdx.x * NTOK;
    bf16_t* pr = P + (size_t)blockIdx.z * pZ + (size_t)blockIdx.x * NTOK;
    int wave = threadIdx.x >> 6, lane = threadIdx.x & 63;
    float v[9];
    float mx = -1e30f;
    #pragma unroll
    for (int t = 0; t < 9; t++) { v[t] = sr[t * 256 + threadIdx.x]; mx = fmaxf(mx, v[t]); }
    for (int off = 32; off > 0; off >>= 1) mx = fmaxf(mx, __shfl_xor(mx, off, 64));
    if (lane == 0) red[wave] = mx;
    __syncthreads();
    mx = fmaxf(fmaxf(red[0], red[1]), fmaxf(red[2], red[3]));
    float sum = 0.f;
    #pragma unroll
    for (int t = 0; t < 9; t++) { v[t] = __expf(v[t] - mx); sum += v[t]; }
    for (int off = 32; off > 0; off >>= 1) sum += __shfl_xor(sum, off, 64);
    if (lane == 0) red[4 + wave] = sum;
    __syncthreads();
    sum = red[4] + red[5] + red[6] + red[7];
    float inv = 1.f / sum;
    #pragma unroll
    for (int t = 0; t < 9; t++) pr[t * 256 + threadIdx.x] = (bf16_t)(v[t] * inv);
}

// ------------------------------------------------------------------
// bf16 MFMA GEMM (attention):  C[M,N] = A[M,K] @ W[N,K]^T
// BM=128, BK=64 (32 MFMA per barrier-pair -> half the vmcnt(0) drains
// of the BK=32 version; LDS 32 KB). 2x2 waves of 64 x (BN/2).
// 128B rows: 8x16B chunks, swizzle chunk^(r&7): frag b128 reads hit 8
// distinct bank-starts x2 lanes = 2-way (free). Staging: 8 rows/issue,
// lane->(row=lane>>3, chunk=lane&7), global chunk = c^(r&7).
// XCD/L2 block swizzle as R4 (verified FETCH 147->77 MB).
// EPI: 1=S f32 (*scale)   2=PV scatter (o_rows)
// ------------------------------------------------------------------
template<int BN, int EPI, int NBY>
__global__ __launch_bounds__(256, 2)
void gemm_bt(const bf16_t* __restrict__ A, const bf16_t* __restrict__ W,
             void* __restrict__ out, int K,
             long long aZ, long long wZ, long long oZ, float scale)
{
    constexpr int BM = 128, BK = 64;
    constexpr int MI = 4;
    constexpr int NT = BN / 32;
    constexpr int NB = 18 * NBY;
    constexpr int CHK = (NB + 7) / 8;
    __shared__ bf16_t As[BM * BK];
    __shared__ bf16_t Bs[BN * BK];

    int id = blockIdx.x;
    int id2 = (id & 7) * CHK + (id >> 3);
    if (id2 >= NB) return;
    int p  = id2 / 108;
    int r_ = id2 - p * 108;
    int by = p * 6 + (r_ % 6);
    int bx = r_ / 6;

    const int tid = threadIdx.x;
    const int wave = tid >> 6, lane = tid & 63;
    const int quad = lane >> 4, l16 = lane & 15;
    const int wm = wave & 1, wn = wave >> 1;
    const int z = blockIdx.z;
    A += (size_t)z * aZ;
    W += (size_t)z * wZ;
    const int m0 = bx * BM, n0 = by * BN;

    f32x4 acc[MI][NT];
    #pragma unroll
    for (int i = 0; i < MI; i++)
        #pragma unroll
        for (int j = 0; j < NT; j++) { f32x4 zz = {0.f, 0.f, 0.f, 0.f}; acc[i][j] = zz; }

    const int srow = lane >> 3;       // row within 8-row issue
    const int scol = lane & 7;        // 16B chunk slot (8 per 128B row)

    for (int k0 = 0; k0 < K; k0 += BK) {
        __syncthreads();
        for (int it = wave; it < BM / 8; it += 4) {
            int r = it * 8 + srow;
            int cg = scol ^ (r & 7);
            gload_lds16(A + (size_t)(m0 + r) * K + k0 + cg * 8, &As[it * 512]);
        }
        for (int it = wave; it < BN / 8; it += 4) {
            int r = it * 8 + srow;
            int cg = scol ^ (r & 7);
            gload_lds16(W + (size_t)(n0 + r) * K + k0 + cg * 8, &Bs[it * 512]);
        }
        __syncthreads();

        bf16x8 af[MI][2], bfr[NT][2];
        #pragma unroll
        for (int i = 0; i < MI; i++) {
            int r = wm * 64 + i * 16 + l16;
            #pragma unroll
            for (int kk = 0; kk < 2; kk++)
                af[i][kk] = *(const bf16x8*)&As[r * 64 + (((kk * 4 + quad) ^ (r & 7)) << 3)];
        }
        #pragma unroll
        for (int j = 0; j < NT; j++) {
            int c = wn * (BN / 2) + j * 16 + l16;
            #pragma unroll
            for (int kk = 0; kk < 2; kk++)
                bfr[j][kk] = *(const bf16x8*)&Bs[c * 64 + (((kk * 4 + quad) ^ (c & 7)) << 3)];
        }
        #pragma unroll
        for (int kk = 0; kk < 2; kk++)
            #pragma unroll
            for (int i = 0; i < MI; i++)
                #pragma unroll
                for (int j = 0; j < NT; j++)
                    acc[i][j] = __builtin_amdgcn_mfma_f32_16x16x32_bf16(af[i][kk], bfr[j][kk], acc[i][j], 0, 0, 0);
    }

    #pragma unroll
    for (int i = 0; i < MI; i++)
        #pragma unroll
        for (int j = 0; j < NT; j++)
            #pragma unroll
            for (int ri = 0; ri < 4; ri++) {
                int r = m0 + wm * 64 + i * 16 + quad * 4 + ri;
                int c = n0 + wn * (BN / 2) + j * 16 + l16;
                float v = acc[i][j][ri];
                if constexpr (EPI == 1) {
                    float* op = (float*)out + (size_t)z * oZ;
                    op[(size_t)r * NTOK + c] = v * scale;
                } else {
                    int b = r / 48, rr = r - b * 48;
                    ((bf16_t*)out)[((size_t)(b * NTOK + rr * 48 + z * 16)) * CDIM + c] = (bf16_t)v;
                }
            }
}

// ------------------------------------------------------------------
// Weight-resident GEMM:  C[M,N] = A[M,K] @ W[N,K]^T, W entirely in LDS.
// 4 waves, BM=256 (64 rows/wave). One barrier total.
// EPI: 0=QKV scatter(+bias)  3=bias+GELU bf16  4=bias+residual f32
//      5=bias+residual -> x2 f32 AND fused LayerNorm -> out2 bf16
//         (row of 96 = 16 lanes x 6 regs; shfl_xor over l16 bits)
// ------------------------------------------------------------------
template<int N, int K, int KC, int EPI>
__global__ __launch_bounds__(256, 2)
void gemm_ws(const bf16_t* __restrict__ A, const bf16_t* __restrict__ Wg,
             void* __restrict__ out, const float* __restrict__ bias,
             const float* __restrict__ resid,
             bf16_t* __restrict__ out2, const float* __restrict__ g2,
             const float* __restrict__ b2)
{
    constexpr int KP = K + 8;
    constexpr int NT = N / 16;
    constexpr int KI = KC / 32;
    __shared__ __attribute__((aligned(16))) bf16_t Ws[N * KP];

    const int tid = threadIdx.x;
    const int wave = tid >> 6, lane = tid & 63;
    const int quad = lane >> 4, l16 = lane & 15;
    const int m0 = blockIdx.x * 256;

    constexpr int CH = N * K / 8;
    for (int c = tid; c < CH; c += 256) {
        int row = c / (K / 8), kc = c - row * (K / 8);
        bf16x8 w = *(const bf16x8*)(Wg + row * K + kc * 8);
        *(bf16x8*)(Ws + row * KP + kc * 8) = w;
    }
    __syncthreads();

    const bf16_t* Ar = A + (size_t)(m0 + wave * 64 + l16) * K + quad * 8;

    const int t = m0 / NTOK;
    const int nb = m0 - t * NTOK;

    auto epi_tile = [&](int nt, const f32x4* a4) {
        int c = nt * 16 + l16;
        if constexpr (EPI == 0) {
            int jj = t * 288 + c;
            int g = jj / FDIM, mm = jj - g * FDIM;
            float bv = bias[c];
            bf16_t* yp = (bf16_t*)out + (size_t)g * YSTR + mm;
            #pragma unroll
            for (int i = 0; i < 4; i++)
                #pragma unroll
                for (int ri = 0; ri < 4; ri++) {
                    int n = nb + wave * 64 + i * 16 + quad * 4 + ri;
                    yp[(size_t)n * FDIM] = (bf16_t)(a4[i][ri] + bv);
                }
        } else {
            float bv = bias[c];
            #pragma unroll
            for (int i = 0; i < 4; i++)
                #pragma unroll
                for (int ri = 0; ri < 4; ri++) {
                    int r = m0 + wave * 64 + i * 16 + quad * 4 + ri;
                    float v = a4[i][ri] + bv;
                    if constexpr (EPI == 3) {
                        v = 0.5f * v * (1.0f + erff(v * 0.70710678118654752f));
                        ((bf16_t*)out)[(size_t)r * N + c] = (bf16_t)v;
                    } else {
                        ((float*)out)[(size_t)r * N + c] = v + resid[(size_t)r * N + c];
                    }
                }
        }
    };

    if constexpr (KC == K && EPI != 5) {
        bf16x8 af[4][KI];
        #pragma unroll
        for (int i = 0; i < 4; i++)
            #pragma unroll
            for (int kk = 0; kk < KI; kk++)
                af[i][kk] = *(const bf16x8*)(Ar + (size_t)i * 16 * K + kk * 32);
        #pragma unroll 2
        for (int nt = 0; nt < NT; nt++) {
            bf16x8 bfr[KI];
            #pragma unroll
            for (int kk = 0; kk < KI; kk++)
                bfr[kk] = *(const bf16x8*)(Ws + (nt * 16 + l16) * KP + kk * 32 + quad * 8);
            f32x4 a4[4];
            #pragma unroll
            for (int i = 0; i < 4; i++) { f32x4 zz = {0.f, 0.f, 0.f, 0.f}; a4[i] = zz; }
            #pragma unroll
            for (int kk = 0; kk < KI; kk++)
                #pragma unroll
                for (int i = 0; i < 4; i++)
                    a4[i] = __builtin_amdgcn_mfma_f32_16x16x32_bf16(af[i][kk], bfr[kk], a4[i], 0, 0, 0);
            epi_tile(nt, a4);
        }
    } else {
        f32x4 acc[4][NT];
        #pragma unroll
        for (int i = 0; i < 4; i++)
            #pragma unroll
            for (int j = 0; j < NT; j++) { f32x4 zz = {0.f, 0.f, 0.f, 0.f}; acc[i][j] = zz; }
        for (int kc0 = 0; kc0 < K; kc0 += KC) {
            bf16x8 af[4][KI];
            #pragma unroll
            for (int i = 0; i < 4; i++)
                #pragma unroll
                for (int kk = 0; kk < KI; kk++)
                    af[i][kk] = *(const bf16x8*)(Ar + (size_t)i * 16 * K + kc0 + kk * 32);
            #pragma unroll
            for (int nt = 0; nt < NT; nt++) {
                #pragma unroll
                for (int kk = 0; kk < KI; kk++) {
                    bf16x8 b = *(const bf16x8*)(Ws + (nt * 16 + l16) * KP + kc0 + kk * 32 + quad * 8);
                    #pragma unroll
                    for (int i = 0; i < 4; i++)
                        acc[i][nt] = __builtin_amdgcn_mfma_f32_16x16x32_bf16(af[i][kk], b, acc[i][nt], 0, 0, 0);
                }
            }
        }
        if constexpr (EPI == 5) {
            // proj + bias + residual -> x2 (f32, out), LN -> out2 (bf16)
            float bv[NT], gv[NT], bb[NT];
            #pragma unroll
            for (int nt = 0; nt < NT; nt++) {
                int c = nt * 16 + l16;
                bv[nt] = bias[c]; gv[nt] = g2[c]; bb[nt] = b2[c];
            }
            #pragma unroll
            for (int i = 0; i < 4; i++)
                #pragma unroll
                for (int ri = 0; ri < 4; ri++) {
                    int r = m0 + wave * 64 + i * 16 + quad * 4 + ri;
                    float u[NT];
                    float s = 0.f;
                    #pragma unroll
                    for (int nt = 0; nt < NT; nt++) {
                        int c = nt * 16 + l16;
                        u[nt] = acc[i][nt][ri] + bv[nt] + resid[(size_t)r * N + c];
                        ((float*)out)[(size_t)r * N + c] = u[nt];
                        s += u[nt];
                    }
                    #pragma unroll
                    for (int off = 8; off > 0; off >>= 1) s += __shfl_xor(s, off, 64);
                    float mean = s * (1.f / 96.f);
                    float vs = 0.f;
                    #pragma unroll
                    for (int nt = 0; nt < NT; nt++) {
                        float dd = u[nt] - mean;
                        u[nt] = dd;
                        vs += dd * dd;
                    }
                    #pragma unroll
                    for (int off = 8; off > 0; off >>= 1) vs += __shfl_xor(vs, off, 64);
                    float rstd = rsqrtf(vs * (1.f / 96.f) + 1e-5f);
                    #pragma unroll
                    for (int nt = 0; nt < NT; nt++) {
                        int c = nt * 16 + l16;
                        out2[(size_t)r * N + c] = (bf16_t)(u[nt] * rstd * gv[nt] + bb[nt]);
                    }
                }
        } else {
            #pragma unroll
            for (int nt = 0; nt < NT; nt++) {
                f32x4 a4[4];
                #pragma unroll
                for (int i = 0; i < 4; i++) a4[i] = acc[i][nt];
                epi_tile(nt, a4);
            }
        }
    }
}

// ------------------------------------------------------------------
extern "C" void kernel_launch(void* const* d_in, const int* in_sizes, int n_in,
                              void* d_out, int out_size, void* d_ws, size_t ws_size,
                              hipStream_t stream)
{
    const float* x      = (const float*)d_in[0];
    const float* ln1_g  = (const float*)d_in[2];
    const float* ln1_b  = (const float*)d_in[3];
    const float* qkv_w  = (const float*)d_in[4];
    const float* qkv_b  = (const float*)d_in[5];
    const float* proj_w = (const float*)d_in[6];
    const float* proj_b = (const float*)d_in[7];
    const float* ln2_g  = (const float*)d_in[8];
    const float* ln2_b  = (const float*)d_in[9];
    const float* fc1_w  = (const float*)d_in[10];
    const float* fc1_b  = (const float*)d_in[11];
    const float* fc2_w  = (const float*)d_in[12];
    const float* fc2_b  = (const float*)d_in[13];

    // ---- workspace layout, 170.1 MB (aliased by liveness; see R4 notes) ----
    const size_t SZ_WB = 110592ull * 2;
    const size_t SZ_HP = 10616832ull * 2;
    const size_t SZ_Y  = 31850496ull * 2;
    const size_t SZ_YV = 10616832ull * 2;

    char* ws = (char*)d_ws;
    size_t oWB = 0;
    size_t oHP = oWB + SZ_WB;
    size_t oY  = oHP + SZ_HP;
    size_t oYV = oY + SZ_Y;
    size_t oS  = oYV + SZ_YV;

    bf16_t* Wb    = (bf16_t*)(ws + oWB);
    bf16_t* Wqkv  = Wb;
    bf16_t* Wproj = Wb + 27648;
    bf16_t* Wfc1  = Wb + 36864;
    bf16_t* Wfc2  = Wb + 73728;
    bf16_t* hp    = (bf16_t*)(ws + oHP);   // ln1out / o_rows / h2
    bf16_t* Y     = (bf16_t*)(ws + oY);
    bf16_t* Yv    = (bf16_t*)(ws + oYV);
    bf16_t* Pb    = (bf16_t*)(ws + oY);    // P aliases Y (Q/K dead)
    bf16_t* t1    = (bf16_t*)(ws + oY);    // t1 aliases Y+YV
    float*  Sb    = (float*)(ws + oS);
    float*  x2    = (float*)(ws + oS);     // x2 aliases S (dead after softmax)
    float*  outp  = (float*)d_out;

    dim3 blk(256);

    // 1. weights -> bf16
    conv_w<<<dim3(432), blk, 0, stream>>>(qkv_w, proj_w, fc1_w, fc2_w, Wb);
    // 2. LN1 + axial permute -> hp [48][2304][96]
    ln4_kernel<<<dim3(13824), blk, 0, stream>>>(x, ln1_g, ln1_b, hp, 1);
    // 3. QKV gemm (W-resident) -> Y scattered
    gemm_ws<288, 96, 96, 0><<<dim3(432), blk, 0, stream>>>(hp, Wqkv, Y, qkv_b,
                                                           nullptr, nullptr, nullptr, nullptr);
    // 4. V transpose -> Yv [h][m][n]
    transpose_v<<<dim3(24, 36, 3), blk, 0, stream>>>(Y, Yv);

    // 5. S = Q@K^T (batched; BK=64)
    gemm_bt<128, 1, 18><<<dim3(328, 1, 3), blk, 0, stream>>>(Y, Y + 3 * YSTR, Sb,
                                                             1536, YSTR, YSTR, SSTR, SCALE_Q);
    // 6. softmax -> P
    softmax_k<<<dim3(2304, 1, 3), blk, 0, stream>>>(Sb, Pb, SSTR, SSTR);
    // 7. O = P@V^T -> o_rows in hp (BK=64)
    gemm_bt<128, 2, 12><<<dim3(216, 1, 3), blk, 0, stream>>>(Pb, Yv, hp,
                                                             2304, SSTR, YSTR, 0, 0.f);

    // 8. proj + residual -> x2 (f32) + fused LN2 -> h2 (hp region)
    gemm_ws<96, 96, 96, 5><<<dim3(432), blk, 0, stream>>>(hp, Wproj, x2, proj_b, x,
                                                          hp, ln2_g, ln2_b);
    // 9. fc1 + GELU -> t1 (aliases Y+YV)
    gemm_ws<384, 96, 96, 3><<<dim3(432), blk, 0, stream>>>(hp, Wfc1, t1, fc1_b,
                                                           nullptr, nullptr, nullptr, nullptr);
    // 10. fc2 + residual -> out (f32; acc-resident, KC=96)
    gemm_ws<96, 384, 96, 4><<<dim3(432), blk, 0, stream>>>(t1, Wfc2, outp, fc2_b, x2,
                                                           nullptr, nullptr, nullptr);
}

// Round 6
// 393.246 us; speedup vs baseline: 1.3051x; 1.0263x over previous
//
#include <hip/hip_runtime.h>
#include <hip/hip_bf16.h>
#include <math.h>

typedef __bf16 bf16_t;
typedef __bf16 bf16x8 __attribute__((ext_vector_type(8)));
typedef __bf16 bf16x4 __attribute__((ext_vector_type(4)));
typedef float f32x4 __attribute__((ext_vector_type(4)));

#define AS1q __attribute__((address_space(1)))
#define AS3q __attribute__((address_space(3)))

__device__ __forceinline__ void gload_lds16(const bf16_t* g, bf16_t* l) {
    __builtin_amdgcn_global_load_lds((AS1q void*)g, (AS3q void*)l, 16, 0, 0);
}

// ------------------------------------------------------------------
// constants (B=1, H=W=T=48, C=96, nh=3, hd=32)
// ------------------------------------------------------------------
#define LROWS   110592
#define CDIM    96
#define NTOK    2304
#define FDIM    1536
#define YSTR    3538944ll     // 2304*1536
#define SSTR    5308416ll     // 2304*2304
#define SCALE_Q 0.1767766952966369f

// ------------------------------------------------------------------
// weight fp32 -> bf16
// ------------------------------------------------------------------
__global__ __launch_bounds__(256)
void conv_w(const float* __restrict__ a, const float* __restrict__ b,
            const float* __restrict__ c, const float* __restrict__ d,
            bf16_t* __restrict__ out)
{
    int i = blockIdx.x * 256 + threadIdx.x;
    float v;
    if (i < 27648)       v = a[i];
    else if (i < 36864)  v = b[i - 27648];
    else if (i < 73728)  v = c[i - 36864];
    else                 v = d[i - 73728];
    out[i] = (bf16_t)v;
}

// ------------------------------------------------------------------
// Vectorized LayerNorm (float4), 8 rows/block, 32 lanes/row.
// permute: src row l = n*48+t -> dst row t*2304+n
// ------------------------------------------------------------------
__global__ __launch_bounds__(256)
void ln4_kernel(const float* __restrict__ x, const float* __restrict__ gamma,
                const float* __restrict__ beta, bf16_t* __restrict__ out, int permute)
{
    int wave = threadIdx.x >> 6;
    int half = (threadIdx.x >> 5) & 1;
    int cl   = threadIdx.x & 31;
    int row  = blockIdx.x * 8 + wave * 2 + half;
    bool act = cl < 24;
    const f32x4* xr = (const f32x4*)(x + (size_t)row * CDIM);
    f32x4 v = {0.f, 0.f, 0.f, 0.f};
    if (act) v = xr[cl];
    float s = v[0] + v[1] + v[2] + v[3];
    #pragma unroll
    for (int off = 16; off > 0; off >>= 1) s += __shfl_xor(s, off, 64);
    float mean = s * (1.f / 96.f);
    f32x4 d = {0.f, 0.f, 0.f, 0.f};
    if (act) { d[0]=v[0]-mean; d[1]=v[1]-mean; d[2]=v[2]-mean; d[3]=v[3]-mean; }
    float vs = d[0]*d[0] + d[1]*d[1] + d[2]*d[2] + d[3]*d[3];
    #pragma unroll
    for (int off = 16; off > 0; off >>= 1) vs += __shfl_xor(vs, off, 64);
    float rstd = rsqrtf(vs * (1.f / 96.f) + 1e-5f);
    size_t orow = row;
    if (permute) { int t = row % 48; int n = row / 48; orow = (size_t)t * NTOK + n; }
    if (act) {
        f32x4 g = ((const f32x4*)gamma)[cl];
        f32x4 b = ((const f32x4*)beta)[cl];
        bf16x4 o;
        #pragma unroll
        for (int j = 0; j < 4; j++) o[j] = (bf16_t)(d[j] * rstd * g[j] + b[j]);
        *(bf16x4*)(out + orow * CDIM + cl * 4) = o;
    }
}

// ------------------------------------------------------------------
// row softmax over 2304, S bf16 -> P bf16.  One WAVE per row (no LDS),
// bf16x4 vector loads/stores: 36 elems/lane.
// ------------------------------------------------------------------
__global__ __launch_bounds__(256)
void softmax_k(const bf16_t* __restrict__ S, bf16_t* __restrict__ P,
               long long sZ, long long pZ)
{
    int wv = threadIdx.x >> 6, lane = threadIdx.x & 63;
    int row = blockIdx.x * 4 + wv;
    const bf16_t* sr = S + (size_t)blockIdx.z * sZ + (size_t)row * NTOK;
    bf16_t* pr = P + (size_t)blockIdx.z * pZ + (size_t)row * NTOK;
    float v[36];
    float mx = -1e30f;
    #pragma unroll
    for (int t = 0; t < 9; t++) {
        bf16x4 c = *(const bf16x4*)(sr + (size_t)(t * 64 + lane) * 4);
        #pragma unroll
        for (int j = 0; j < 4; j++) { v[t*4+j] = (float)c[j]; mx = fmaxf(mx, v[t*4+j]); }
    }
    #pragma unroll
    for (int off = 32; off > 0; off >>= 1) mx = fmaxf(mx, __shfl_xor(mx, off, 64));
    float sum = 0.f;
    #pragma unroll
    for (int j = 0; j < 36; j++) { v[j] = __expf(v[j] - mx); sum += v[j]; }
    #pragma unroll
    for (int off = 32; off > 0; off >>= 1) sum += __shfl_xor(sum, off, 64);
    float inv = 1.f / sum;
    #pragma unroll
    for (int t = 0; t < 9; t++) {
        bf16x4 o;
        #pragma unroll
        for (int j = 0; j < 4; j++) o[j] = (bf16_t)(v[t*4+j] * inv);
        *(bf16x4*)(pr + (size_t)(t * 64 + lane) * 4) = o;
    }
}

// ------------------------------------------------------------------
// bf16 MFMA GEMM (attention):  C[M,N] = A[M,K] @ W[N,K]^T
// BM=128, BK=64, 2x2 waves; XOR swizzle chunk^(r&7) -> 0 conflicts (R5).
// XCD/L2 block swizzle (R4: FETCH 147->77 MB).
// EPI: 1=S bf16 (*scale)   2=PV scatter (o_rows)
// ------------------------------------------------------------------
template<int BN, int EPI, int NBY>
__global__ __launch_bounds__(256, 2)
void gemm_bt(const bf16_t* __restrict__ A, const bf16_t* __restrict__ W,
             void* __restrict__ out, int K,
             long long aZ, long long wZ, long long oZ, float scale)
{
    constexpr int BM = 128, BK = 64;
    constexpr int MI = 4;
    constexpr int NT = BN / 32;
    constexpr int NB = 18 * NBY;
    constexpr int CHK = (NB + 7) / 8;
    __shared__ bf16_t As[BM * BK];
    __shared__ bf16_t Bs[BN * BK];

    int id = blockIdx.x;
    int id2 = (id & 7) * CHK + (id >> 3);
    if (id2 >= NB) return;
    int p  = id2 / 108;
    int r_ = id2 - p * 108;
    int by = p * 6 + (r_ % 6);
    int bx = r_ / 6;

    const int tid = threadIdx.x;
    const int wave = tid >> 6, lane = tid & 63;
    const int quad = lane >> 4, l16 = lane & 15;
    const int wm = wave & 1, wn = wave >> 1;
    const int z = blockIdx.z;
    A += (size_t)z * aZ;
    W += (size_t)z * wZ;
    const int m0 = bx * BM, n0 = by * BN;

    f32x4 acc[MI][NT];
    #pragma unroll
    for (int i = 0; i < MI; i++)
        #pragma unroll
        for (int j = 0; j < NT; j++) { f32x4 zz = {0.f, 0.f, 0.f, 0.f}; acc[i][j] = zz; }

    const int srow = lane >> 3;
    const int scol = lane & 7;

    for (int k0 = 0; k0 < K; k0 += BK) {
        __syncthreads();
        for (int it = wave; it < BM / 8; it += 4) {
            int r = it * 8 + srow;
            int cg = scol ^ (r & 7);
            gload_lds16(A + (size_t)(m0 + r) * K + k0 + cg * 8, &As[it * 512]);
        }
        for (int it = wave; it < BN / 8; it += 4) {
            int r = it * 8 + srow;
            int cg = scol ^ (r & 7);
            gload_lds16(W + (size_t)(n0 + r) * K + k0 + cg * 8, &Bs[it * 512]);
        }
        __syncthreads();

        bf16x8 af[MI][2], bfr[NT][2];
        #pragma unroll
        for (int i = 0; i < MI; i++) {
            int r = wm * 64 + i * 16 + l16;
            #pragma unroll
            for (int kk = 0; kk < 2; kk++)
                af[i][kk] = *(const bf16x8*)&As[r * 64 + (((kk * 4 + quad) ^ (r & 7)) << 3)];
        }
        #pragma unroll
        for (int j = 0; j < NT; j++) {
            int c = wn * (BN / 2) + j * 16 + l16;
            #pragma unroll
            for (int kk = 0; kk < 2; kk++)
                bfr[j][kk] = *(const bf16x8*)&Bs[c * 64 + (((kk * 4 + quad) ^ (c & 7)) << 3)];
        }
        #pragma unroll
        for (int kk = 0; kk < 2; kk++)
            #pragma unroll
            for (int i = 0; i < MI; i++)
                #pragma unroll
                for (int j = 0; j < NT; j++)
                    acc[i][j] = __builtin_amdgcn_mfma_f32_16x16x32_bf16(af[i][kk], bfr[j][kk], acc[i][j], 0, 0, 0);
    }

    #pragma unroll
    for (int i = 0; i < MI; i++)
        #pragma unroll
        for (int j = 0; j < NT; j++)
            #pragma unroll
            for (int ri = 0; ri < 4; ri++) {
                int r = m0 + wm * 64 + i * 16 + quad * 4 + ri;
                int c = n0 + wn * (BN / 2) + j * 16 + l16;
                float v = acc[i][j][ri];
                if constexpr (EPI == 1) {
                    bf16_t* op = (bf16_t*)out + (size_t)z * oZ;
                    op[(size_t)r * NTOK + c] = (bf16_t)(v * scale);
                } else {
                    int b = r / 48, rr = r - b * 48;
                    ((bf16_t*)out)[((size_t)(b * NTOK + rr * 48 + z * 16)) * CDIM + c] = (bf16_t)v;
                }
            }
}

// ------------------------------------------------------------------
// Weight-resident GEMM:  C[M,N] = A[M,K] @ W[N,K]^T, W in LDS, BM=256.
// EPI 0: QKV scatter(+bias); V part (g>=6) written DIRECTLY TRANSPOSED
//        to out2=Yv[h][m][n] as bf16x4 (replaces transpose_v kernel;
//        16-col tiles never straddle a g-boundary -> g uniform per tile)
// EPI 5: proj+bias+residual -> out f32 AND fused LayerNorm -> out2 bf16
// ------------------------------------------------------------------
template<int N, int K, int KC, int EPI>
__global__ __launch_bounds__(256, 2)
void gemm_ws(const bf16_t* __restrict__ A, const bf16_t* __restrict__ Wg,
             void* __restrict__ out, const float* __restrict__ bias,
             const float* __restrict__ resid,
             bf16_t* __restrict__ out2, const float* __restrict__ g2,
             const float* __restrict__ b2)
{
    constexpr int KP = K + 8;
    constexpr int NT = N / 16;
    constexpr int KI = KC / 32;
    __shared__ __attribute__((aligned(16))) bf16_t Ws[N * KP];

    const int tid = threadIdx.x;
    const int wave = tid >> 6, lane = tid & 63;
    const int quad = lane >> 4, l16 = lane & 15;
    const int m0 = blockIdx.x * 256;

    constexpr int CH = N * K / 8;
    for (int c = tid; c < CH; c += 256) {
        int row = c / (K / 8), kc = c - row * (K / 8);
        bf16x8 w = *(const bf16x8*)(Wg + row * K + kc * 8);
        *(bf16x8*)(Ws + row * KP + kc * 8) = w;
    }
    __syncthreads();

    const bf16_t* Ar = A + (size_t)(m0 + wave * 64 + l16) * K + quad * 8;

    const int t = m0 / NTOK;
    const int nb = m0 - t * NTOK;

    auto epi_tile = [&](int nt, const f32x4* a4) {
        int c = nt * 16 + l16;
        if constexpr (EPI == 0) {
            int jj = t * 288 + c;
            int g = jj / FDIM, mm = jj - g * FDIM;
            float bv = bias[c];
            if (g < 6) {
                bf16_t* yp = (bf16_t*)out + (size_t)g * YSTR + mm;
                #pragma unroll
                for (int i = 0; i < 4; i++)
                    #pragma unroll
                    for (int ri = 0; ri < 4; ri++) {
                        int n = nb + wave * 64 + i * 16 + quad * 4 + ri;
                        yp[(size_t)n * FDIM] = (bf16_t)(a4[i][ri] + bv);
                    }
            } else {
                // V: write transposed -> Yv[g-6][mm][n], contiguous in ri
                bf16_t* vp = out2 + (size_t)(g - 6) * YSTR + (size_t)mm * NTOK;
                #pragma unroll
                for (int i = 0; i < 4; i++) {
                    int n0q = nb + wave * 64 + i * 16 + quad * 4;
                    bf16x4 o;
                    #pragma unroll
                    for (int ri = 0; ri < 4; ri++) o[ri] = (bf16_t)(a4[i][ri] + bv);
                    *(bf16x4*)(vp + n0q) = o;
                }
            }
        } else {
            float bv = bias[c];
            #pragma unroll
            for (int i = 0; i < 4; i++)
                #pragma unroll
                for (int ri = 0; ri < 4; ri++) {
                    int r = m0 + wave * 64 + i * 16 + quad * 4 + ri;
                    float v = a4[i][ri] + bv;
                    if constexpr (EPI == 3) {
                        v = 0.5f * v * (1.0f + erff(v * 0.70710678118654752f));
                        ((bf16_t*)out)[(size_t)r * N + c] = (bf16_t)v;
                    } else {
                        ((float*)out)[(size_t)r * N + c] = v + resid[(size_t)r * N + c];
                    }
                }
        }
    };

    if constexpr (KC == K && EPI != 5) {
        bf16x8 af[4][KI];
        #pragma unroll
        for (int i = 0; i < 4; i++)
            #pragma unroll
            for (int kk = 0; kk < KI; kk++)
                af[i][kk] = *(const bf16x8*)(Ar + (size_t)i * 16 * K + kk * 32);
        #pragma unroll 2
        for (int nt = 0; nt < NT; nt++) {
            bf16x8 bfr[KI];
            #pragma unroll
            for (int kk = 0; kk < KI; kk++)
                bfr[kk] = *(const bf16x8*)(Ws + (nt * 16 + l16) * KP + kk * 32 + quad * 8);
            f32x4 a4[4];
            #pragma unroll
            for (int i = 0; i < 4; i++) { f32x4 zz = {0.f, 0.f, 0.f, 0.f}; a4[i] = zz; }
            #pragma unroll
            for (int kk = 0; kk < KI; kk++)
                #pragma unroll
                for (int i = 0; i < 4; i++)
                    a4[i] = __builtin_amdgcn_mfma_f32_16x16x32_bf16(af[i][kk], bfr[kk], a4[i], 0, 0, 0);
            epi_tile(nt, a4);
        }
    } else {
        f32x4 acc[4][NT];
        #pragma unroll
        for (int i = 0; i < 4; i++)
            #pragma unroll
            for (int j = 0; j < NT; j++) { f32x4 zz = {0.f, 0.f, 0.f, 0.f}; acc[i][j] = zz; }
        for (int kc0 = 0; kc0 < K; kc0 += KC) {
            bf16x8 af[4][KI];
            #pragma unroll
            for (int i = 0; i < 4; i++)
                #pragma unroll
                for (int kk = 0; kk < KI; kk++)
                    af[i][kk] = *(const bf16x8*)(Ar + (size_t)i * 16 * K + kc0 + kk * 32);
            #pragma unroll
            for (int nt = 0; nt < NT; nt++) {
                #pragma unroll
                for (int kk = 0; kk < KI; kk++) {
                    bf16x8 b = *(const bf16x8*)(Ws + (nt * 16 + l16) * KP + kc0 + kk * 32 + quad * 8);
                    #pragma unroll
                    for (int i = 0; i < 4; i++)
                        acc[i][nt] = __builtin_amdgcn_mfma_f32_16x16x32_bf16(af[i][kk], b, acc[i][nt], 0, 0, 0);
                }
            }
        }
        if constexpr (EPI == 5) {
            float bv[NT], gv[NT], bb[NT];
            #pragma unroll
            for (int nt = 0; nt < NT; nt++) {
                int c = nt * 16 + l16;
                bv[nt] = bias[c]; gv[nt] = g2[c]; bb[nt] = b2[c];
            }
            #pragma unroll
            for (int i = 0; i < 4; i++)
                #pragma unroll
                for (int ri = 0; ri < 4; ri++) {
                    int r = m0 + wave * 64 + i * 16 + quad * 4 + ri;
                    float u[NT];
                    float s = 0.f;
                    #pragma unroll
                    for (int nt = 0; nt < NT; nt++) {
                        int c = nt * 16 + l16;
                        u[nt] = acc[i][nt][ri] + bv[nt] + resid[(size_t)r * N + c];
                        ((float*)out)[(size_t)r * N + c] = u[nt];
                        s += u[nt];
                    }
                    #pragma unroll
                    for (int off = 8; off > 0; off >>= 1) s += __shfl_xor(s, off, 64);
                    float mean = s * (1.f / 96.f);
                    float vs = 0.f;
                    #pragma unroll
                    for (int nt = 0; nt < NT; nt++) {
                        float dd = u[nt] - mean;
                        u[nt] = dd;
                        vs += dd * dd;
                    }
                    #pragma unroll
                    for (int off = 8; off > 0; off >>= 1) vs += __shfl_xor(vs, off, 64);
                    float rstd = rsqrtf(vs * (1.f / 96.f) + 1e-5f);
                    #pragma unroll
                    for (int nt = 0; nt < NT; nt++) {
                        int c = nt * 16 + l16;
                        out2[(size_t)r * N + c] = (bf16_t)(u[nt] * rstd * gv[nt] + bb[nt]);
                    }
                }
        } else {
            #pragma unroll
            for (int nt = 0; nt < NT; nt++) {
                f32x4 a4[4];
                #pragma unroll
                for (int i = 0; i < 4; i++) a4[i] = acc[i][nt];
                epi_tile(nt, a4);
            }
        }
    }
}

// ------------------------------------------------------------------
// Fused MLP: out = x2 + fc2(gelu(fc1(h2)+b1))+b2   (t1 never hits HBM)
// BM=256, 4 waves. W1 [384][96+8] resident in LDS (79.9KB); per 32-col
// chunk: fc1 (24 MFMA) -> GELU -> C-layout->A-layout via Tb[256][40]
// (20.5KB, 18-dword rows: 16 distinct bank starts) -> fc2 partial
// (24 MFMA) vs W2 chunk [96][40] restaged per chunk (7.7KB, prefetched
// to VGPRs before fc1 to hide latency). LDS total 108KB -> 1 block/CU.
// Barriers are LDS-only (no vmcnt drain of a deep queue).
// ------------------------------------------------------------------
__global__ __launch_bounds__(256, 1)
void mlp_fused(const bf16_t* __restrict__ A, const bf16_t* __restrict__ W1g,
               const bf16_t* __restrict__ W2g, const float* __restrict__ b1,
               const float* __restrict__ b2, const float* __restrict__ resid,
               float* __restrict__ out)
{
    constexpr int KP1 = 104;
    __shared__ __attribute__((aligned(16))) bf16_t W1s[384 * KP1]; // 79872 B
    __shared__ __attribute__((aligned(16))) bf16_t W2c[96 * 40];   //  7680 B
    __shared__ __attribute__((aligned(16))) bf16_t Tb[256 * 40];   // 20480 B

    const int tid = threadIdx.x;
    const int wave = tid >> 6, lane = tid & 63;
    const int quad = lane >> 4, l16 = lane & 15;
    const int m0 = blockIdx.x * 256;

    // stage W1 (384x96)
    for (int c = tid; c < 384 * 12; c += 256) {
        int row = c / 12, kc = c - row * 12;
        bf16x8 w = *(const bf16x8*)(W1g + row * 96 + kc * 8);
        *(bf16x8*)(W1s + row * KP1 + kc * 8) = w;
    }

    // A rows resident (full K=96)
    const bf16_t* Ar = A + (size_t)(m0 + wave * 64 + l16) * 96 + quad * 8;
    bf16x8 af[4][3];
    #pragma unroll
    for (int i = 0; i < 4; i++)
        #pragma unroll
        for (int kk = 0; kk < 3; kk++)
            af[i][kk] = *(const bf16x8*)(Ar + (size_t)i * 16 * 96 + kk * 32);

    __syncthreads();

    f32x4 acc2[4][6];
    #pragma unroll
    for (int i = 0; i < 4; i++)
        #pragma unroll
        for (int j = 0; j < 6; j++) { f32x4 zz = {0.f, 0.f, 0.f, 0.f}; acc2[i][j] = zz; }

    for (int c = 0; c < 12; c++) {
        // prefetch W2 chunk (96 rows x 32 cols) to VGPRs
        bf16x4 w2r[3];
        #pragma unroll
        for (int q = 0; q < 3; q++) {
            int e = q * 256 + tid;
            int row = e >> 3, sub = e & 7;
            w2r[q] = *(const bf16x4*)(W2g + row * 384 + c * 32 + sub * 4);
        }
        // fc1 chunk: cols c*32..+32
        f32x4 a1[4][2];
        #pragma unroll
        for (int i = 0; i < 4; i++)
            #pragma unroll
            for (int s = 0; s < 2; s++) { f32x4 zz = {0.f, 0.f, 0.f, 0.f}; a1[i][s] = zz; }
        #pragma unroll
        for (int s = 0; s < 2; s++) {
            int n = c * 32 + s * 16 + l16;
            #pragma unroll
            for (int kk = 0; kk < 3; kk++) {
                bf16x8 b = *(const bf16x8*)(W1s + n * KP1 + kk * 32 + quad * 8);
                #pragma unroll
                for (int i = 0; i < 4; i++)
                    a1[i][s] = __builtin_amdgcn_mfma_f32_16x16x32_bf16(af[i][kk], b, a1[i][s], 0, 0, 0);
            }
        }
        __syncthreads();   // prev chunk's Tb/W2c reads done
        // GELU -> Tb (C-layout scatter); W2c <- prefetched regs
        #pragma unroll
        for (int s = 0; s < 2; s++) {
            int n = c * 32 + s * 16 + l16;
            float bv = b1[n];
            #pragma unroll
            for (int i = 0; i < 4; i++)
                #pragma unroll
                for (int ri = 0; ri < 4; ri++) {
                    float u = a1[i][s][ri] + bv;
                    u = 0.5f * u * (1.0f + erff(u * 0.70710678118654752f));
                    Tb[(wave * 64 + i * 16 + quad * 4 + ri) * 40 + s * 16 + l16] = (bf16_t)u;
                }
        }
        #pragma unroll
        for (int q = 0; q < 3; q++) {
            int e = q * 256 + tid;
            int row = e >> 3, sub = e & 7;
            *(bf16x4*)(W2c + row * 40 + sub * 4) = w2r[q];
        }
        __syncthreads();
        // fc2 partial (K=32)
        bf16x8 a2[4];
        #pragma unroll
        for (int i = 0; i < 4; i++)
            a2[i] = *(const bf16x8*)(Tb + (wave * 64 + i * 16 + l16) * 40 + quad * 8);
        #pragma unroll
        for (int nt = 0; nt < 6; nt++) {
            bf16x8 b = *(const bf16x8*)(W2c + (nt * 16 + l16) * 40 + quad * 8);
            #pragma unroll
            for (int i = 0; i < 4; i++)
                acc2[i][nt] = __builtin_amdgcn_mfma_f32_16x16x32_bf16(a2[i], b, acc2[i][nt], 0, 0, 0);
        }
    }

    // epilogue: + b2 + resid -> f32 out
    #pragma unroll
    for (int i = 0; i < 4; i++)
        #pragma unroll
        for (int nt = 0; nt < 6; nt++)
            #pragma unroll
            for (int ri = 0; ri < 4; ri++) {
                int r = m0 + wave * 64 + i * 16 + quad * 4 + ri;
                int cc = nt * 16 + l16;
                out[(size_t)r * 96 + cc] = acc2[i][nt][ri] + b2[cc] + resid[(size_t)r * 96 + cc];
            }
}

// ------------------------------------------------------------------
extern "C" void kernel_launch(void* const* d_in, const int* in_sizes, int n_in,
                              void* d_out, int out_size, void* d_ws, size_t ws_size,
                              hipStream_t stream)
{
    const float* x      = (const float*)d_in[0];
    const float* ln1_g  = (const float*)d_in[2];
    const float* ln1_b  = (const float*)d_in[3];
    const float* qkv_w  = (const float*)d_in[4];
    const float* qkv_b  = (const float*)d_in[5];
    const float* proj_w = (const float*)d_in[6];
    const float* proj_b = (const float*)d_in[7];
    const float* ln2_g  = (const float*)d_in[8];
    const float* ln2_b  = (const float*)d_in[9];
    const float* fc1_w  = (const float*)d_in[10];
    const float* fc1_b  = (const float*)d_in[11];
    const float* fc2_w  = (const float*)d_in[12];
    const float* fc2_b  = (const float*)d_in[13];

    // ---- workspace 170.1 MB (aliased by liveness) ----
    // [WB][HP: ln1out->o_rows->h2][Y: QKV q/k -> P][YV: V direct][S: S bf16 -> x2]
    const size_t SZ_WB = 110592ull * 2;
    const size_t SZ_HP = 10616832ull * 2;
    const size_t SZ_Y  = 31850496ull * 2;
    const size_t SZ_YV = 10616832ull * 2;

    char* ws = (char*)d_ws;
    size_t oWB = 0;
    size_t oHP = oWB + SZ_WB;
    size_t oY  = oHP + SZ_HP;
    size_t oYV = oY + SZ_Y;
    size_t oS  = oYV + SZ_YV;

    bf16_t* Wb    = (bf16_t*)(ws + oWB);
    bf16_t* Wqkv  = Wb;
    bf16_t* Wproj = Wb + 27648;
    bf16_t* Wfc1  = Wb + 36864;
    bf16_t* Wfc2  = Wb + 73728;
    bf16_t* hp    = (bf16_t*)(ws + oHP);   // ln1out / o_rows / h2
    bf16_t* Y     = (bf16_t*)(ws + oY);    // q,k (g 0..5); V goes straight to Yv
    bf16_t* Yv    = (bf16_t*)(ws + oYV);
    bf16_t* Pb    = (bf16_t*)(ws + oY);    // P aliases Y (q/k dead after S)
    bf16_t* Sb    = (bf16_t*)(ws + oS);    // S bf16
    float*  x2    = (float*)(ws + oS);     // x2 aliases S (dead after softmax)
    float*  outp  = (float*)d_out;

    dim3 blk(256);

    // 1. weights -> bf16
    conv_w<<<dim3(432), blk, 0, stream>>>(qkv_w, proj_w, fc1_w, fc2_w, Wb);
    // 2. LN1 + axial permute -> hp
    ln4_kernel<<<dim3(13824), blk, 0, stream>>>(x, ln1_g, ln1_b, hp, 1);
    // 3. QKV gemm -> Y (q,k) + Yv (V transposed, fused)
    gemm_ws<288, 96, 96, 0><<<dim3(432), blk, 0, stream>>>(hp, Wqkv, Y, qkv_b,
                                                           nullptr, Yv, nullptr, nullptr);
    // 4. S = Q@K^T -> bf16
    gemm_bt<128, 1, 18><<<dim3(328, 1, 3), blk, 0, stream>>>(Y, Y + 3 * YSTR, Sb,
                                                             1536, YSTR, YSTR, SSTR, SCALE_Q);
    // 5. softmax (wave/row, vectorized) -> P
    softmax_k<<<dim3(576, 1, 3), blk, 0, stream>>>(Sb, Pb, SSTR, SSTR);
    // 6. O = P@V^T -> o_rows in hp
    gemm_bt<128, 2, 12><<<dim3(216, 1, 3), blk, 0, stream>>>(Pb, Yv, hp,
                                                             2304, SSTR, YSTR, 0, 0.f);
    // 7. proj + residual -> x2 (f32) + fused LN2 -> h2 (hp)
    gemm_ws<96, 96, 96, 5><<<dim3(432), blk, 0, stream>>>(hp, Wproj, x2, proj_b, x,
                                                          hp, ln2_g, ln2_b);
    // 8. fused MLP (fc1+GELU+fc2+residual) -> out
    mlp_fused<<<dim3(432), blk, 0, stream>>>(hp, Wfc1, Wfc2, fc1_b, fc2_b, x2, outp);
}

// Round 7
// 350.308 us; speedup vs baseline: 1.4651x; 1.1226x over previous
//
#include <hip/hip_runtime.h>
#include <hip/hip_bf16.h>
#include <math.h>

typedef __bf16 bf16_t;
typedef __bf16 bf16x8 __attribute__((ext_vector_type(8)));
typedef __bf16 bf16x4 __attribute__((ext_vector_type(4)));
typedef float f32x4 __attribute__((ext_vector_type(4)));

#define AS1q __attribute__((address_space(1)))
#define AS3q __attribute__((address_space(3)))

__device__ __forceinline__ void gload_lds16(const bf16_t* g, bf16_t* l) {
    __builtin_amdgcn_global_load_lds((AS1q void*)g, (AS3q void*)l, 16, 0, 0);
}

// ------------------------------------------------------------------
// constants (B=1, H=W=T=48, C=96, nh=3, hd=32)
// ------------------------------------------------------------------
#define LROWS   110592
#define CDIM    96
#define NTOK    2304
#define FDIM    1536
#define YSTR    3538944ll     // 2304*1536
#define SSTR    5308416ll     // 2304*2304
#define SCALE_Q 0.1767766952966369f

// ------------------------------------------------------------------
// weight fp32 -> bf16
// ------------------------------------------------------------------
__global__ __launch_bounds__(256)
void conv_w(const float* __restrict__ a, const float* __restrict__ b,
            const float* __restrict__ c, const float* __restrict__ d,
            bf16_t* __restrict__ out)
{
    int i = blockIdx.x * 256 + threadIdx.x;
    float v;
    if (i < 27648)       v = a[i];
    else if (i < 36864)  v = b[i - 27648];
    else if (i < 73728)  v = c[i - 36864];
    else                 v = d[i - 73728];
    out[i] = (bf16_t)v;
}

// ------------------------------------------------------------------
// Vectorized LayerNorm (float4), 8 rows/block, 32 lanes/row.
// permute: src row l = n*48+t -> dst row t*2304+n
// ------------------------------------------------------------------
__global__ __launch_bounds__(256)
void ln4_kernel(const float* __restrict__ x, const float* __restrict__ gamma,
                const float* __restrict__ beta, bf16_t* __restrict__ out, int permute)
{
    int wave = threadIdx.x >> 6;
    int half = (threadIdx.x >> 5) & 1;
    int cl   = threadIdx.x & 31;
    int row  = blockIdx.x * 8 + wave * 2 + half;
    bool act = cl < 24;
    const f32x4* xr = (const f32x4*)(x + (size_t)row * CDIM);
    f32x4 v = {0.f, 0.f, 0.f, 0.f};
    if (act) v = xr[cl];
    float s = v[0] + v[1] + v[2] + v[3];
    #pragma unroll
    for (int off = 16; off > 0; off >>= 1) s += __shfl_xor(s, off, 64);
    float mean = s * (1.f / 96.f);
    f32x4 d = {0.f, 0.f, 0.f, 0.f};
    if (act) { d[0]=v[0]-mean; d[1]=v[1]-mean; d[2]=v[2]-mean; d[3]=v[3]-mean; }
    float vs = d[0]*d[0] + d[1]*d[1] + d[2]*d[2] + d[3]*d[3];
    #pragma unroll
    for (int off = 16; off > 0; off >>= 1) vs += __shfl_xor(vs, off, 64);
    float rstd = rsqrtf(vs * (1.f / 96.f) + 1e-5f);
    size_t orow = row;
    if (permute) { int t = row % 48; int n = row / 48; orow = (size_t)t * NTOK + n; }
    if (act) {
        f32x4 g = ((const f32x4*)gamma)[cl];
        f32x4 b = ((const f32x4*)beta)[cl];
        bf16x4 o;
        #pragma unroll
        for (int j = 0; j < 4; j++) o[j] = (bf16_t)(d[j] * rstd * g[j] + b[j]);
        *(bf16x4*)(out + orow * CDIM + cl * 4) = o;
    }
}

// ------------------------------------------------------------------
// row softmax over 2304, S bf16 -> P bf16.  One WAVE per row (no LDS).
// ------------------------------------------------------------------
__global__ __launch_bounds__(256)
void softmax_k(const bf16_t* __restrict__ S, bf16_t* __restrict__ P,
               long long sZ, long long pZ)
{
    int wv = threadIdx.x >> 6, lane = threadIdx.x & 63;
    int row = blockIdx.x * 4 + wv;
    const bf16_t* sr = S + (size_t)blockIdx.z * sZ + (size_t)row * NTOK;
    bf16_t* pr = P + (size_t)blockIdx.z * pZ + (size_t)row * NTOK;
    float v[36];
    float mx = -1e30f;
    #pragma unroll
    for (int t = 0; t < 9; t++) {
        bf16x4 c = *(const bf16x4*)(sr + (size_t)(t * 64 + lane) * 4);
        #pragma unroll
        for (int j = 0; j < 4; j++) { v[t*4+j] = (float)c[j]; mx = fmaxf(mx, v[t*4+j]); }
    }
    #pragma unroll
    for (int off = 32; off > 0; off >>= 1) mx = fmaxf(mx, __shfl_xor(mx, off, 64));
    float sum = 0.f;
    #pragma unroll
    for (int j = 0; j < 36; j++) { v[j] = __expf(v[j] - mx); sum += v[j]; }
    #pragma unroll
    for (int off = 32; off > 0; off >>= 1) sum += __shfl_xor(sum, off, 64);
    float inv = 1.f / sum;
    #pragma unroll
    for (int t = 0; t < 9; t++) {
        bf16x4 o;
        #pragma unroll
        for (int j = 0; j < 4; j++) o[j] = (bf16_t)(v[t*4+j] * inv);
        *(bf16x4*)(pr + (size_t)(t * 64 + lane) * 4) = o;
    }
}

// ------------------------------------------------------------------
// bf16 MFMA GEMM (attention):  C[M,N] = A[M,K] @ W[N,K]^T
// BM=128, BK=64, 2x2 waves; XOR swizzle chunk^(r&7) -> 0 conflicts (R5).
// XCD/L2 block swizzle (R4: FETCH 147->77 MB).
// EPI: 1=S bf16 (*scale)   2=PV scatter (o_rows)
// ------------------------------------------------------------------
template<int BN, int EPI, int NBY>
__global__ __launch_bounds__(256, 2)
void gemm_bt(const bf16_t* __restrict__ A, const bf16_t* __restrict__ W,
             void* __restrict__ out, int K,
             long long aZ, long long wZ, long long oZ, float scale)
{
    constexpr int BM = 128, BK = 64;
    constexpr int MI = 4;
    constexpr int NT = BN / 32;
    constexpr int NB = 18 * NBY;
    constexpr int CHK = (NB + 7) / 8;
    __shared__ bf16_t As[BM * BK];
    __shared__ bf16_t Bs[BN * BK];

    int id = blockIdx.x;
    int id2 = (id & 7) * CHK + (id >> 3);
    if (id2 >= NB) return;
    int p  = id2 / 108;
    int r_ = id2 - p * 108;
    int by = p * 6 + (r_ % 6);
    int bx = r_ / 6;

    const int tid = threadIdx.x;
    const int wave = tid >> 6, lane = tid & 63;
    const int quad = lane >> 4, l16 = lane & 15;
    const int wm = wave & 1, wn = wave >> 1;
    const int z = blockIdx.z;
    A += (size_t)z * aZ;
    W += (size_t)z * wZ;
    const int m0 = bx * BM, n0 = by * BN;

    f32x4 acc[MI][NT];
    #pragma unroll
    for (int i = 0; i < MI; i++)
        #pragma unroll
        for (int j = 0; j < NT; j++) { f32x4 zz = {0.f, 0.f, 0.f, 0.f}; acc[i][j] = zz; }

    const int srow = lane >> 3;
    const int scol = lane & 7;

    for (int k0 = 0; k0 < K; k0 += BK) {
        __syncthreads();
        for (int it = wave; it < BM / 8; it += 4) {
            int r = it * 8 + srow;
            int cg = scol ^ (r & 7);
            gload_lds16(A + (size_t)(m0 + r) * K + k0 + cg * 8, &As[it * 512]);
        }
        for (int it = wave; it < BN / 8; it += 4) {
            int r = it * 8 + srow;
            int cg = scol ^ (r & 7);
            gload_lds16(W + (size_t)(n0 + r) * K + k0 + cg * 8, &Bs[it * 512]);
        }
        __syncthreads();

        bf16x8 af[MI][2], bfr[NT][2];
        #pragma unroll
        for (int i = 0; i < MI; i++) {
            int r = wm * 64 + i * 16 + l16;
            #pragma unroll
            for (int kk = 0; kk < 2; kk++)
                af[i][kk] = *(const bf16x8*)&As[r * 64 + (((kk * 4 + quad) ^ (r & 7)) << 3)];
        }
        #pragma unroll
        for (int j = 0; j < NT; j++) {
            int c = wn * (BN / 2) + j * 16 + l16;
            #pragma unroll
            for (int kk = 0; kk < 2; kk++)
                bfr[j][kk] = *(const bf16x8*)&Bs[c * 64 + (((kk * 4 + quad) ^ (c & 7)) << 3)];
        }
        #pragma unroll
        for (int kk = 0; kk < 2; kk++)
            #pragma unroll
            for (int i = 0; i < MI; i++)
                #pragma unroll
                for (int j = 0; j < NT; j++)
                    acc[i][j] = __builtin_amdgcn_mfma_f32_16x16x32_bf16(af[i][kk], bfr[j][kk], acc[i][j], 0, 0, 0);
    }

    #pragma unroll
    for (int i = 0; i < MI; i++)
        #pragma unroll
        for (int j = 0; j < NT; j++)
            #pragma unroll
            for (int ri = 0; ri < 4; ri++) {
                int r = m0 + wm * 64 + i * 16 + quad * 4 + ri;
                int c = n0 + wn * (BN / 2) + j * 16 + l16;
                float v = acc[i][j][ri];
                if constexpr (EPI == 1) {
                    bf16_t* op = (bf16_t*)out + (size_t)z * oZ;
                    op[(size_t)r * NTOK + c] = (bf16_t)(v * scale);
                } else {
                    int b = r / 48, rr = r - b * 48;
                    ((bf16_t*)out)[((size_t)(b * NTOK + rr * 48 + z * 16)) * CDIM + c] = (bf16_t)v;
                }
            }
}

// ------------------------------------------------------------------
// Weight-resident GEMM:  C[M,N] = A[M,K] @ W[N,K]^T, W in LDS, BM=256.
// EPI 0: QKV scatter(+bias); V part (g>=6) written DIRECTLY TRANSPOSED
// EPI 5: proj+bias+residual -> out f32 AND fused LayerNorm -> out2 bf16
// ------------------------------------------------------------------
template<int N, int K, int KC, int EPI>
__global__ __launch_bounds__(256, 2)
void gemm_ws(const bf16_t* __restrict__ A, const bf16_t* __restrict__ Wg,
             void* __restrict__ out, const float* __restrict__ bias,
             const float* __restrict__ resid,
             bf16_t* __restrict__ out2, const float* __restrict__ g2,
             const float* __restrict__ b2)
{
    constexpr int KP = K + 8;
    constexpr int NT = N / 16;
    constexpr int KI = KC / 32;
    __shared__ __attribute__((aligned(16))) bf16_t Ws[N * KP];

    const int tid = threadIdx.x;
    const int wave = tid >> 6, lane = tid & 63;
    const int quad = lane >> 4, l16 = lane & 15;
    const int m0 = blockIdx.x * 256;

    constexpr int CH = N * K / 8;
    for (int c = tid; c < CH; c += 256) {
        int row = c / (K / 8), kc = c - row * (K / 8);
        bf16x8 w = *(const bf16x8*)(Wg + row * K + kc * 8);
        *(bf16x8*)(Ws + row * KP + kc * 8) = w;
    }
    __syncthreads();

    const bf16_t* Ar = A + (size_t)(m0 + wave * 64 + l16) * K + quad * 8;

    const int t = m0 / NTOK;
    const int nb = m0 - t * NTOK;

    auto epi_tile = [&](int nt, const f32x4* a4) {
        int c = nt * 16 + l16;
        if constexpr (EPI == 0) {
            int jj = t * 288 + c;
            int g = jj / FDIM, mm = jj - g * FDIM;
            float bv = bias[c];
            if (g < 6) {
                bf16_t* yp = (bf16_t*)out + (size_t)g * YSTR + mm;
                #pragma unroll
                for (int i = 0; i < 4; i++)
                    #pragma unroll
                    for (int ri = 0; ri < 4; ri++) {
                        int n = nb + wave * 64 + i * 16 + quad * 4 + ri;
                        yp[(size_t)n * FDIM] = (bf16_t)(a4[i][ri] + bv);
                    }
            } else {
                bf16_t* vp = out2 + (size_t)(g - 6) * YSTR + (size_t)mm * NTOK;
                #pragma unroll
                for (int i = 0; i < 4; i++) {
                    int n0q = nb + wave * 64 + i * 16 + quad * 4;
                    bf16x4 o;
                    #pragma unroll
                    for (int ri = 0; ri < 4; ri++) o[ri] = (bf16_t)(a4[i][ri] + bv);
                    *(bf16x4*)(vp + n0q) = o;
                }
            }
        } else {
            float bv = bias[c];
            #pragma unroll
            for (int i = 0; i < 4; i++)
                #pragma unroll
                for (int ri = 0; ri < 4; ri++) {
                    int r = m0 + wave * 64 + i * 16 + quad * 4 + ri;
                    float v = a4[i][ri] + bv;
                    if constexpr (EPI == 3) {
                        v = 0.5f * v * (1.0f + erff(v * 0.70710678118654752f));
                        ((bf16_t*)out)[(size_t)r * N + c] = (bf16_t)v;
                    } else {
                        ((float*)out)[(size_t)r * N + c] = v + resid[(size_t)r * N + c];
                    }
                }
        }
    };

    if constexpr (KC == K && EPI != 5) {
        bf16x8 af[4][KI];
        #pragma unroll
        for (int i = 0; i < 4; i++)
            #pragma unroll
            for (int kk = 0; kk < KI; kk++)
                af[i][kk] = *(const bf16x8*)(Ar + (size_t)i * 16 * K + kk * 32);
        #pragma unroll 2
        for (int nt = 0; nt < NT; nt++) {
            bf16x8 bfr[KI];
            #pragma unroll
            for (int kk = 0; kk < KI; kk++)
                bfr[kk] = *(const bf16x8*)(Ws + (nt * 16 + l16) * KP + kk * 32 + quad * 8);
            f32x4 a4[4];
            #pragma unroll
            for (int i = 0; i < 4; i++) { f32x4 zz = {0.f, 0.f, 0.f, 0.f}; a4[i] = zz; }
            #pragma unroll
            for (int kk = 0; kk < KI; kk++)
                #pragma unroll
                for (int i = 0; i < 4; i++)
                    a4[i] = __builtin_amdgcn_mfma_f32_16x16x32_bf16(af[i][kk], bfr[kk], a4[i], 0, 0, 0);
            epi_tile(nt, a4);
        }
    } else {
        f32x4 acc[4][NT];
        #pragma unroll
        for (int i = 0; i < 4; i++)
            #pragma unroll
            for (int j = 0; j < NT; j++) { f32x4 zz = {0.f, 0.f, 0.f, 0.f}; acc[i][j] = zz; }
        for (int kc0 = 0; kc0 < K; kc0 += KC) {
            bf16x8 af[4][KI];
            #pragma unroll
            for (int i = 0; i < 4; i++)
                #pragma unroll
                for (int kk = 0; kk < KI; kk++)
                    af[i][kk] = *(const bf16x8*)(Ar + (size_t)i * 16 * K + kc0 + kk * 32);
            #pragma unroll
            for (int nt = 0; nt < NT; nt++) {
                #pragma unroll
                for (int kk = 0; kk < KI; kk++) {
                    bf16x8 b = *(const bf16x8*)(Ws + (nt * 16 + l16) * KP + kc0 + kk * 32 + quad * 8);
                    #pragma unroll
                    for (int i = 0; i < 4; i++)
                        acc[i][nt] = __builtin_amdgcn_mfma_f32_16x16x32_bf16(af[i][kk], b, acc[i][nt], 0, 0, 0);
                }
            }
        }
        if constexpr (EPI == 5) {
            float bv[NT], gv[NT], bb[NT];
            #pragma unroll
            for (int nt = 0; nt < NT; nt++) {
                int c = nt * 16 + l16;
                bv[nt] = bias[c]; gv[nt] = g2[c]; bb[nt] = b2[c];
            }
            #pragma unroll
            for (int i = 0; i < 4; i++)
                #pragma unroll
                for (int ri = 0; ri < 4; ri++) {
                    int r = m0 + wave * 64 + i * 16 + quad * 4 + ri;
                    float u[NT];
                    float s = 0.f;
                    #pragma unroll
                    for (int nt = 0; nt < NT; nt++) {
                        int c = nt * 16 + l16;
                        u[nt] = acc[i][nt][ri] + bv[nt] + resid[(size_t)r * N + c];
                        ((float*)out)[(size_t)r * N + c] = u[nt];
                        s += u[nt];
                    }
                    #pragma unroll
                    for (int off = 8; off > 0; off >>= 1) s += __shfl_xor(s, off, 64);
                    float mean = s * (1.f / 96.f);
                    float vs = 0.f;
                    #pragma unroll
                    for (int nt = 0; nt < NT; nt++) {
                        float dd = u[nt] - mean;
                        u[nt] = dd;
                        vs += dd * dd;
                    }
                    #pragma unroll
                    for (int off = 8; off > 0; off >>= 1) vs += __shfl_xor(vs, off, 64);
                    float rstd = rsqrtf(vs * (1.f / 96.f) + 1e-5f);
                    #pragma unroll
                    for (int nt = 0; nt < NT; nt++) {
                        int c = nt * 16 + l16;
                        out2[(size_t)r * N + c] = (bf16_t)(u[nt] * rstd * gv[nt] + bb[nt]);
                    }
                }
        } else {
            #pragma unroll
            for (int nt = 0; nt < NT; nt++) {
                f32x4 a4[4];
                #pragma unroll
                for (int i = 0; i < 4; i++) a4[i] = acc[i][nt];
                epi_tile(nt, a4);
            }
        }
    }
}

// ------------------------------------------------------------------
// Fused MLP v2: out = x2 + fc2(gelu(fc1(h2)+b1))+b2  (t1 never in HBM)
// BM=128 (864 blocks = 3.4/CU grid), 4 waves x 32 rows.
// W1/W2 per-32-col-chunk, DOUBLE-BUFFERED in LDS via reg-prefetch ->
// ds_write under the existing chunk barrier.  LDS = 2x6.5K (W1c) +
// 2x7.5K (W2c) + 10K (Tb) = 48 KB -> 3 blocks/CU (R6's 108KB full-W1
// residence gave 1 block/CU, Occ 9%, MfmaUtil 5.8% -> 107us).
// Barriers are LDS-scoped; co-resident blocks hide them (m114).
// ------------------------------------------------------------------
__global__ __launch_bounds__(256, 3)
void mlp_fused(const bf16_t* __restrict__ A, const bf16_t* __restrict__ W1g,
               const bf16_t* __restrict__ W2g, const float* __restrict__ b1,
               const float* __restrict__ b2, const float* __restrict__ resid,
               float* __restrict__ out)
{
    constexpr int KP1 = 104;   // 96+8: B-frag rows stride 52 dwords -> 2-way (free)
    __shared__ __attribute__((aligned(16))) bf16_t W1c[2][32 * KP1]; // 2x6656 B
    __shared__ __attribute__((aligned(16))) bf16_t W2c[2][96 * 40];  // 2x7680 B
    __shared__ __attribute__((aligned(16))) bf16_t Tb[128 * 40];     // 10240 B

    const int tid = threadIdx.x;
    const int wave = tid >> 6, lane = tid & 63;
    const int quad = lane >> 4, l16 = lane & 15;
    const int m0 = blockIdx.x * 128;

    // A rows resident (full K=96): wave handles 32 rows (2 m-tiles)
    const bf16_t* Ar = A + (size_t)(m0 + wave * 32 + l16) * 96 + quad * 8;
    bf16x8 af[2][3];
    #pragma unroll
    for (int i = 0; i < 2; i++)
        #pragma unroll
        for (int kk = 0; kk < 3; kk++)
            af[i][kk] = *(const bf16x8*)(Ar + (size_t)i * 16 * 96 + kk * 32);

    // prefetch chunk 0 of W1 (32x96) and W2 (96 x cols 0..32) to regs
    bf16x4 w1n[3], w2n[3];
    #pragma unroll
    for (int q = 0; q < 3; q++) {
        int e = q * 256 + tid;
        w1n[q] = *(const bf16x4*)(W1g + e * 4);                       // rows 0..32 contiguous
        int row = e >> 3, sub = e & 7;
        w2n[q] = *(const bf16x4*)(W2g + row * 384 + sub * 4);
    }
    #pragma unroll
    for (int q = 0; q < 3; q++) {
        int e = q * 256 + tid;
        int r1 = e / 24, s1 = e - r1 * 24;
        *(bf16x4*)(&W1c[0][r1 * KP1 + s1 * 4]) = w1n[q];
        int row = e >> 3, sub = e & 7;
        *(bf16x4*)(&W2c[0][row * 40 + sub * 4]) = w2n[q];
    }
    __syncthreads();

    f32x4 acc2[2][6];
    #pragma unroll
    for (int i = 0; i < 2; i++)
        #pragma unroll
        for (int j = 0; j < 6; j++) { f32x4 zz = {0.f, 0.f, 0.f, 0.f}; acc2[i][j] = zz; }

    for (int c = 0; c < 12; c++) {
        const int pb = c & 1;
        // prefetch chunk c+1 to regs (vmcnt hidden by fc1 MFMAs)
        if (c < 11) {
            #pragma unroll
            for (int q = 0; q < 3; q++) {
                int e = q * 256 + tid;
                w1n[q] = *(const bf16x4*)(W1g + (c + 1) * 3072 + e * 4);
                int row = e >> 3, sub = e & 7;
                w2n[q] = *(const bf16x4*)(W2g + row * 384 + (c + 1) * 32 + sub * 4);
            }
        }
        // fc1 chunk: cols c*32..+32  (12 MFMA/wave)
        f32x4 a1[2][2];
        #pragma unroll
        for (int i = 0; i < 2; i++)
            #pragma unroll
            for (int s = 0; s < 2; s++) { f32x4 zz = {0.f, 0.f, 0.f, 0.f}; a1[i][s] = zz; }
        #pragma unroll
        for (int s = 0; s < 2; s++) {
            int n = s * 16 + l16;
            #pragma unroll
            for (int kk = 0; kk < 3; kk++) {
                bf16x8 b = *(const bf16x8*)(&W1c[pb][n * KP1 + kk * 32 + quad * 8]);
                #pragma unroll
                for (int i = 0; i < 2; i++)
                    a1[i][s] = __builtin_amdgcn_mfma_f32_16x16x32_bf16(af[i][kk], b, a1[i][s], 0, 0, 0);
            }
        }
        __syncthreads();   // all waves done reading Tb (c-1 fc2) + W1c[pb] (fc1)
        // GELU -> Tb; stage next chunk's W1/W2 into the other buffers
        #pragma unroll
        for (int s = 0; s < 2; s++) {
            int n = c * 32 + s * 16 + l16;
            float bv = b1[n];
            #pragma unroll
            for (int i = 0; i < 2; i++)
                #pragma unroll
                for (int ri = 0; ri < 4; ri++) {
                    float u = a1[i][s][ri] + bv;
                    u = 0.5f * u * (1.0f + erff(u * 0.70710678118654752f));
                    Tb[(wave * 32 + i * 16 + quad * 4 + ri) * 40 + s * 16 + l16] = (bf16_t)u;
                }
        }
        if (c < 11) {
            #pragma unroll
            for (int q = 0; q < 3; q++) {
                int e = q * 256 + tid;
                int r1 = e / 24, s1 = e - r1 * 24;
                *(bf16x4*)(&W1c[pb ^ 1][r1 * KP1 + s1 * 4]) = w1n[q];
                int row = e >> 3, sub = e & 7;
                *(bf16x4*)(&W2c[pb ^ 1][row * 40 + sub * 4]) = w2n[q];
            }
        }
        __syncthreads();
        // fc2 partial (K=32): 12 MFMA/wave
        bf16x8 a2[2];
        #pragma unroll
        for (int i = 0; i < 2; i++)
            a2[i] = *(const bf16x8*)(Tb + (wave * 32 + i * 16 + l16) * 40 + quad * 8);
        #pragma unroll
        for (int nt = 0; nt < 6; nt++) {
            bf16x8 b = *(const bf16x8*)(&W2c[pb][(nt * 16 + l16) * 40 + quad * 8]);
            #pragma unroll
            for (int i = 0; i < 2; i++)
                acc2[i][nt] = __builtin_amdgcn_mfma_f32_16x16x32_bf16(a2[i], b, acc2[i][nt], 0, 0, 0);
        }
    }

    // epilogue: + b2 + resid -> f32 out
    #pragma unroll
    for (int i = 0; i < 2; i++)
        #pragma unroll
        for (int nt = 0; nt < 6; nt++)
            #pragma unroll
            for (int ri = 0; ri < 4; ri++) {
                int r = m0 + wave * 32 + i * 16 + quad * 4 + ri;
                int cc = nt * 16 + l16;
                out[(size_t)r * 96 + cc] = acc2[i][nt][ri] + b2[cc] + resid[(size_t)r * 96 + cc];
            }
}

// ------------------------------------------------------------------
extern "C" void kernel_launch(void* const* d_in, const int* in_sizes, int n_in,
                              void* d_out, int out_size, void* d_ws, size_t ws_size,
                              hipStream_t stream)
{
    const float* x      = (const float*)d_in[0];
    const float* ln1_g  = (const float*)d_in[2];
    const float* ln1_b  = (const float*)d_in[3];
    const float* qkv_w  = (const float*)d_in[4];
    const float* qkv_b  = (const float*)d_in[5];
    const float* proj_w = (const float*)d_in[6];
    const float* proj_b = (const float*)d_in[7];
    const float* ln2_g  = (const float*)d_in[8];
    const float* ln2_b  = (const float*)d_in[9];
    const float* fc1_w  = (const float*)d_in[10];
    const float* fc1_b  = (const float*)d_in[11];
    const float* fc2_w  = (const float*)d_in[12];
    const float* fc2_b  = (const float*)d_in[13];

    // ---- workspace 170.1 MB (aliased by liveness) ----
    const size_t SZ_WB = 110592ull * 2;
    const size_t SZ_HP = 10616832ull * 2;
    const size_t SZ_Y  = 31850496ull * 2;
    const size_t SZ_YV = 10616832ull * 2;

    char* ws = (char*)d_ws;
    size_t oWB = 0;
    size_t oHP = oWB + SZ_WB;
    size_t oY  = oHP + SZ_HP;
    size_t oYV = oY + SZ_Y;
    size_t oS  = oYV + SZ_YV;

    bf16_t* Wb    = (bf16_t*)(ws + oWB);
    bf16_t* Wqkv  = Wb;
    bf16_t* Wproj = Wb + 27648;
    bf16_t* Wfc1  = Wb + 36864;
    bf16_t* Wfc2  = Wb + 73728;
    bf16_t* hp    = (bf16_t*)(ws + oHP);   // ln1out / o_rows / h2
    bf16_t* Y     = (bf16_t*)(ws + oY);    // q,k; V goes straight to Yv
    bf16_t* Yv    = (bf16_t*)(ws + oYV);
    bf16_t* Pb    = (bf16_t*)(ws + oY);    // P aliases Y
    bf16_t* Sb    = (bf16_t*)(ws + oS);    // S bf16
    float*  x2    = (float*)(ws + oS);     // x2 aliases S
    float*  outp  = (float*)d_out;

    dim3 blk(256);

    // 1. weights -> bf16
    conv_w<<<dim3(432), blk, 0, stream>>>(qkv_w, proj_w, fc1_w, fc2_w, Wb);
    // 2. LN1 + axial permute -> hp
    ln4_kernel<<<dim3(13824), blk, 0, stream>>>(x, ln1_g, ln1_b, hp, 1);
    // 3. QKV gemm -> Y (q,k) + Yv (V transposed, fused)
    gemm_ws<288, 96, 96, 0><<<dim3(432), blk, 0, stream>>>(hp, Wqkv, Y, qkv_b,
                                                           nullptr, Yv, nullptr, nullptr);
    // 4. S = Q@K^T -> bf16
    gemm_bt<128, 1, 18><<<dim3(328, 1, 3), blk, 0, stream>>>(Y, Y + 3 * YSTR, Sb,
                                                             1536, YSTR, YSTR, SSTR, SCALE_Q);
    // 5. softmax (wave/row, vectorized) -> P
    softmax_k<<<dim3(576, 1, 3), blk, 0, stream>>>(Sb, Pb, SSTR, SSTR);
    // 6. O = P@V^T -> o_rows in hp
    gemm_bt<128, 2, 12><<<dim3(216, 1, 3), blk, 0, stream>>>(Pb, Yv, hp,
                                                             2304, SSTR, YSTR, 0, 0.f);
    // 7. proj + residual -> x2 (f32) + fused LN2 -> h2 (hp)
    gemm_ws<96, 96, 96, 5><<<dim3(432), blk, 0, stream>>>(hp, Wproj, x2, proj_b, x,
                                                          hp, ln2_g, ln2_b);
    // 8. fused MLP v2 (fc1+GELU+fc2+residual) -> out
    mlp_fused<<<dim3(864), blk, 0, stream>>>(hp, Wfc1, Wfc2, fc1_b, fc2_b, x2, outp);
}